// Round 22
// baseline (124.189 us; speedup 1.0000x reference)
//
#include <hip/hip_runtime.h>
#include <hip/hip_fp16.h>

typedef float fvec4 __attribute__((ext_vector_type(4)));
typedef int ivec4 __attribute__((ext_vector_type(4)));

#define NN 65536      // total nodes per side (B*NPG)
#define EE 1048576    // edges per side (B*NPG*DEG)
#define BB 128
#define NPG 512
#define EPG 8192      // edges per graph (NPG*DEG)

__device__ __forceinline__ int pkrtz(float a, float b) {
  union { __half2 h; int i; } u; u.h = __floats2half2_rn(a, b); return u.i;
}
__device__ __forceinline__ float2 up2(int v) {
  union { int i; __half2 h; } u; u.i = v; return __half22float2(u.h);
}

// accumulate one 16B quad (8 f16) into two fvec4 f32 partial sums
#define ACCQ(SA, SB, w) { float2 f_; \
  f_ = up2((w)[0]); (SA)[0] += f_.x; (SA)[1] += f_.y; \
  f_ = up2((w)[1]); (SA)[2] += f_.x; (SA)[3] += f_.y; \
  f_ = up2((w)[2]); (SB)[0] += f_.x; (SB)[1] += f_.y; \
  f_ = up2((w)[3]); (SB)[2] += f_.x; (SB)[3] += f_.y; }

__device__ __forceinline__ int slot_of(int node) {
  constexpr int srows[20] = {25, 26, 76, 77, 127, 128, 178, 179, 229, 230,
                             281, 282, 332, 333, 383, 384, 434, 435, 485, 486};
  int slot = -1;
#pragma unroll
  for (int i = 0; i < 20; ++i)
    if (node == srows[i]) slot = i;
  return slot;
}
__constant__ int c_srows[20] = {25, 26, 76, 77, 127, 128, 178, 179, 229, 230,
                                281, 282, 332, 333, 383, 384, 434, 435, 485, 486};

// ================= kP: per (side,graph): CSR build once -> sidsG/packG =================
__global__ __launch_bounds__(512)
void kP(const int* __restrict__ ei, const int* __restrict__ ej,
        unsigned short* __restrict__ sidsG, unsigned int* __restrict__ packG) {
  __shared__ unsigned short dsts[EPG];    // 16 KB
  __shared__ unsigned short sids[EPG];    // 16 KB
  __shared__ int cnt[NPG];
  __shared__ int posb[NPG];
  __shared__ int wsum[8];
  const int sg = blockIdx.x;
  const int side = sg >> 7, g = sg & 127;
  const int* __restrict__ eidx = side ? ej : ei;
  const int v = threadIdx.x;
  const int base = g * NPG, ebase = g * EPG;

  cnt[v] = 0;
  __syncthreads();
  for (int k = v; k < EPG; k += 512) {
    int d = eidx[EE + ebase + k] - base;
    dsts[k] = (unsigned short)d;
    atomicAdd(&cnt[d], 1);
  }
  __syncthreads();

  const int count = cnt[v];
  int xa = count;
  const int lane = v & 63;
#pragma unroll
  for (int d = 1; d < 64; d <<= 1) {
    int y = __shfl_up(xa, d, 64);
    if (lane >= d) xa += y;
  }
  const int wid = v >> 6;
  if (lane == 63) wsum[wid] = xa;
  __syncthreads();
  if (v == 0) {
    int a = 0;
#pragma unroll
    for (int i = 0; i < 8; ++i) { int tv = wsum[i]; wsum[i] = a; a += tv; }
  }
  __syncthreads();
  const int start = xa - count + wsum[wid];
  posb[v] = start;
  packG[sg * NPG + v] = ((unsigned int)start << 16) | (unsigned int)count;
  __syncthreads();

  for (int k = v; k < EPG; k += 512) {
    int lv = eidx[ebase + k] - base;
    int p = atomicAdd(&posb[dsts[k]], 1);
    sids[p] = (unsigned short)lv;
  }
  __syncthreads();

  const int* srcI = reinterpret_cast<const int*>(sids);
  int* dstI = reinterpret_cast<int*>(sidsG + (size_t)sg * EPG);
  for (int k = v; k < EPG / 2; k += 512) dstI[k] = srcI[k];
}

// ================= kA: per (side,graph,half): L0 half + y1 partial =================
// 512 blocks x 512 threads; LDS 48KB -> 3 blocks/CU (24 waves/CU).
__global__ __launch_bounds__(512)
void kA(const float* __restrict__ x_i, const float* __restrict__ x_j,
        const float* __restrict__ gw0, const float* __restrict__ gb0,
        const float* __restrict__ gw1,
        const unsigned short* __restrict__ sidsG, const unsigned int* __restrict__ packG,
        float* __restrict__ hs0, unsigned int* __restrict__ y1G) {
  __shared__ ivec4 buf[NPG * 4];          // 32 KB f16 msg rows (4 quads/node)
  __shared__ unsigned short sids[EPG];    // 16 KB
  const int bid = blockIdx.x;
  const int half = bid & 1;
  const int sg = bid >> 1;
  const int side = sg >> 7, g = sg & 127;
  const float* __restrict__ x = side ? x_j : x_i;
  const int v = threadIdx.x;
  const int base = g * NPG;

  {
    const int* srcI = reinterpret_cast<const int*>(sidsG + (size_t)sg * EPG);
    int* dstI = reinterpret_cast<int*>(sids);
    for (int k = v; k < EPG / 2; k += 512) dstI[k] = srcI[k];
  }
  const unsigned int pack = packG[sg * NPG + v];
  const int count = (int)(pack & 0xffffu);
  const int nstart = (int)(pack >> 16);
  const float inv_v = rsqrtf((float)count + 1.0f);

  // ---- L0 half-GEMM: a0 = x_row @ W0[:, half*32 : half*32+32] ----
  fvec4 a0[8];
#pragma unroll
  for (int q = 0; q < 8; ++q) a0[q] = fvec4{0.f, 0.f, 0.f, 0.f};
  {
    const fvec4* xv = reinterpret_cast<const fvec4*>(x + (size_t)(base + v) * 64);
    const float* w0h = gw0 + half * 32;
#pragma unroll 1
    for (int k16 = 0; k16 < 4; ++k16) {
      fvec4 xq[4];
#pragma unroll
      for (int u = 0; u < 4; ++u) xq[u] = xv[4 * k16 + u];
#pragma unroll
      for (int u = 0; u < 4; ++u) {
#pragma unroll
        for (int j = 0; j < 4; ++j) {
          const float xk = xq[u][j];
          const fvec4* wr = reinterpret_cast<const fvec4*>(w0h + (size_t)(16 * k16 + 4 * u + j) * 64);
#pragma unroll
          for (int q = 0; q < 8; ++q) a0[q] += xk * wr[q];
        }
      }
    }
  }

  // ---- publish own messages (f16, swizzled) ----
  const int myKey = (v << 2) | ((v >> 1) & 3);
  fvec4 s[8];
#pragma unroll
  for (int q = 0; q < 8; ++q) s[q] = a0[q] * inv_v;
#pragma unroll
  for (int q_ = 0; q_ < 4; ++q_) {
    ivec4 w_;
    w_[0] = pkrtz(s[2 * q_][0], s[2 * q_][1]);
    w_[1] = pkrtz(s[2 * q_][2], s[2 * q_][3]);
    w_[2] = pkrtz(s[2 * q_ + 1][0], s[2 * q_ + 1][1]);
    w_[3] = pkrtz(s[2 * q_ + 1][2], s[2 * q_ + 1][3]);
    buf[myKey ^ q_] = w_;
  }
  __syncthreads();

  // ---- gather 32 feats (unroll x2, keys from raw ids) ----
  {
    int e = nstart;
    const int end = nstart + count;
    for (; e + 2 <= end; e += 2) {
      const int la = sids[e], lb = sids[e + 1];
      const int Ka = (la << 2) | ((la >> 1) & 3);
      const int Kb = (lb << 2) | ((lb >> 1) & 3);
      const ivec4 a0_ = buf[Ka], a1_ = buf[Ka ^ 1], a2_ = buf[Ka ^ 2], a3_ = buf[Ka ^ 3];
      const ivec4 b0_ = buf[Kb], b1_ = buf[Kb ^ 1], b2_ = buf[Kb ^ 2], b3_ = buf[Kb ^ 3];
      ACCQ(s[0], s[1], a0_) ACCQ(s[2], s[3], a1_) ACCQ(s[4], s[5], a2_) ACCQ(s[6], s[7], a3_)
      ACCQ(s[0], s[1], b0_) ACCQ(s[2], s[3], b1_) ACCQ(s[4], s[5], b2_) ACCQ(s[6], s[7], b3_)
    }
    if (e < end) {
      const int la = sids[e];
      const int Ka = (la << 2) | ((la >> 1) & 3);
      const ivec4 a0_ = buf[Ka], a1_ = buf[Ka ^ 1], a2_ = buf[Ka ^ 2], a3_ = buf[Ka ^ 3];
      ACCQ(s[0], s[1], a0_) ACCQ(s[2], s[3], a1_) ACCQ(s[4], s[5], a2_) ACCQ(s[6], s[7], a3_)
    }
  }

  // ---- epilogue: h0_half = relu(s*inv + b); hs0 slice; fold y1P = h0_half @ W1[half rows] ----
  const int slot = slot_of(v);
  const int hb = (side * BB + g) * 20;
  fvec4 y1P[8];
#pragma unroll
  for (int p = 0; p < 8; ++p) y1P[p] = fvec4{0.f, 0.f, 0.f, 0.f};
  {
    const fvec4* gb0v = reinterpret_cast<const fvec4*>(gb0 + half * 32);
    fvec4* hp = reinterpret_cast<fvec4*>(hs0 + ((size_t)hb + slot) * 64 + half * 32);
#pragma unroll
    for (int q = 0; q < 8; ++q) {
      fvec4 o = s[q] * inv_v + gb0v[q];
#pragma unroll
      for (int j = 0; j < 4; ++j) o[j] = fmaxf(o[j], 0.f);
      if (slot >= 0) hp[q] = o;
#pragma unroll
      for (int j = 0; j < 4; ++j) {
        const float hf = o[j];
        const fvec4* wr = reinterpret_cast<const fvec4*>(gw1 + (size_t)(half * 32 + q * 4 + j) * 32);
#pragma unroll
        for (int p = 0; p < 8; ++p) y1P[p] += hf * wr[p];
      }
    }
  }
  {
    unsigned int* yp = y1G + ((size_t)(sg * 2 + half) * NPG + v) * 16;
#pragma unroll
    for (int w = 0; w < 16; ++w)
      yp[w] = (unsigned int)pkrtz(y1P[w >> 1][(w & 1) * 2], y1P[w >> 1][(w & 1) * 2 + 1]);
  }
}

// ================= kB: per (side,graph,half): L1 (16-feat slice) + y2 partial =================
__global__ __launch_bounds__(512)
void kB(const float* __restrict__ gb1, const float* __restrict__ gw2,
        const unsigned short* __restrict__ sidsG, const unsigned int* __restrict__ packG,
        const unsigned int* __restrict__ y1G,
        float* __restrict__ hs1, unsigned int* __restrict__ y2G) {
  __shared__ ivec4 buf[NPG * 2];          // 16 KB: msg rows of 2 quads
  __shared__ unsigned short sids[EPG];    // 16 KB
  const int bid = blockIdx.x;
  const int half = bid & 1;
  const int sg = bid >> 1;
  const int side = sg >> 7, g = sg & 127;
  const int v = threadIdx.x;

  {
    const int* srcI = reinterpret_cast<const int*>(sidsG + (size_t)sg * EPG);
    int* dstI = reinterpret_cast<int*>(sids);
    for (int k = v; k < EPG / 2; k += 512) dstI[k] = srcI[k];
  }
  const unsigned int pack = packG[sg * NPG + v];
  const int count = (int)(pack & 0xffffu);
  const int nstart = (int)(pack >> 16);
  const float inv_v = rsqrtf((float)count + 1.0f);

  // ---- y1 slice = sum of both halves' partials (16 f32) ----
  fvec4 s1[4];
  {
    const unsigned int* p0 = y1G + ((size_t)(sg * 2 + 0) * NPG + v) * 16 + half * 8;
    const unsigned int* p1 = y1G + ((size_t)(sg * 2 + 1) * NPG + v) * 16 + half * 8;
#pragma unroll
    for (int w = 0; w < 8; ++w) {
      float2 fa = up2((int)p0[w]);
      float2 fb = up2((int)p1[w]);
      s1[w >> 1][(w & 1) * 2] = (fa.x + fb.x) * inv_v;
      s1[w >> 1][(w & 1) * 2 + 1] = (fa.y + fb.y) * inv_v;
    }
  }
  // ---- publish 16 f16 (2 quads), key1 = (v<<1)|(v&1) ----
  const int myKey = (v << 1) | (v & 1);
  {
    ivec4 w0, w1;
    w0[0] = pkrtz(s1[0][0], s1[0][1]); w0[1] = pkrtz(s1[0][2], s1[0][3]);
    w0[2] = pkrtz(s1[1][0], s1[1][1]); w0[3] = pkrtz(s1[1][2], s1[1][3]);
    w1[0] = pkrtz(s1[2][0], s1[2][1]); w1[1] = pkrtz(s1[2][2], s1[2][3]);
    w1[2] = pkrtz(s1[3][0], s1[3][1]); w1[3] = pkrtz(s1[3][2], s1[3][3]);
    buf[myKey] = w0;
    buf[myKey ^ 1] = w1;
  }
  __syncthreads();

  // ---- gather 16 feats (unroll x2) ----
  {
    int e = nstart;
    const int end = nstart + count;
    for (; e + 2 <= end; e += 2) {
      const int la = sids[e], lb = sids[e + 1];
      const int Ka = (la << 1) | (la & 1), Kb = (lb << 1) | (lb & 1);
      const ivec4 a0_ = buf[Ka], a1_ = buf[Ka ^ 1];
      const ivec4 b0_ = buf[Kb], b1_ = buf[Kb ^ 1];
      ACCQ(s1[0], s1[1], a0_) ACCQ(s1[2], s1[3], a1_)
      ACCQ(s1[0], s1[1], b0_) ACCQ(s1[2], s1[3], b1_)
    }
    if (e < end) {
      const int la = sids[e];
      const int Ka = (la << 1) | (la & 1);
      const ivec4 a0_ = buf[Ka], a1_ = buf[Ka ^ 1];
      ACCQ(s1[0], s1[1], a0_) ACCQ(s1[2], s1[3], a1_)
    }
  }

  // ---- epilogue: h1_half = relu(s1*inv + b); hs1 slice; fold y2P = h1_half @ W2[half rows] ----
  const int slot = slot_of(v);
  const int hb = (side * BB + g) * 20;
  fvec4 y2P[4];
#pragma unroll
  for (int p = 0; p < 4; ++p) y2P[p] = fvec4{0.f, 0.f, 0.f, 0.f};
  {
    const fvec4* gb1v = reinterpret_cast<const fvec4*>(gb1 + half * 16);
    fvec4* hp = reinterpret_cast<fvec4*>(hs1 + ((size_t)hb + slot) * 32 + half * 16);
#pragma unroll
    for (int q = 0; q < 4; ++q) {
      fvec4 o = s1[q] * inv_v + gb1v[q];
#pragma unroll
      for (int j = 0; j < 4; ++j) o[j] = fmaxf(o[j], 0.f);
      if (slot >= 0) hp[q] = o;
#pragma unroll
      for (int j = 0; j < 4; ++j) {
        const float hf = o[j];
        const fvec4* wr = reinterpret_cast<const fvec4*>(gw2 + (size_t)(half * 16 + q * 4 + j) * 16);
#pragma unroll
        for (int p = 0; p < 4; ++p) y2P[p] += hf * wr[p];
      }
    }
  }
  {
    unsigned int* yp = y2G + ((size_t)(sg * 2 + half) * NPG + v) * 8;
#pragma unroll
    for (int w = 0; w < 8; ++w)
      yp[w] = (unsigned int)pkrtz(y2P[w >> 1][(w & 1) * 2], y2P[w >> 1][(w & 1) * 2 + 1]);
  }
}

// ================= kC: per (side,graph): L2 gather for sampled rows only =================
__global__ __launch_bounds__(512)
void kC(const float* __restrict__ gb2,
        const unsigned short* __restrict__ sidsG, const unsigned int* __restrict__ packG,
        const unsigned int* __restrict__ y2G, float* __restrict__ hs2) {
  __shared__ ivec4 buf[NPG * 2];          // 16 KB
  __shared__ unsigned short sids[EPG];    // 16 KB
  const int sg = blockIdx.x;
  const int side = sg >> 7, g = sg & 127;
  const int v = threadIdx.x;

  {
    const int* srcI = reinterpret_cast<const int*>(sidsG + (size_t)sg * EPG);
    int* dstI = reinterpret_cast<int*>(sids);
    for (int k = v; k < EPG / 2; k += 512) dstI[k] = srcI[k];
  }
  const unsigned int pack = packG[sg * NPG + v];
  const int count = (int)(pack & 0xffffu);
  const float inv_v = rsqrtf((float)count + 1.0f);

  // y2 full = sum of both halves' partials; publish msg = y2*inv (16 f16)
  const int myKey = (v << 1) | (v & 1);
  {
    const unsigned int* p0 = y2G + ((size_t)(sg * 2 + 0) * NPG + v) * 8;
    const unsigned int* p1 = y2G + ((size_t)(sg * 2 + 1) * NPG + v) * 8;
    fvec4 y2[4];
#pragma unroll
    for (int w = 0; w < 8; ++w) {
      float2 fa = up2((int)p0[w]);
      float2 fb = up2((int)p1[w]);
      y2[w >> 1][(w & 1) * 2] = (fa.x + fb.x) * inv_v;
      y2[w >> 1][(w & 1) * 2 + 1] = (fa.y + fb.y) * inv_v;
    }
    ivec4 w0, w1;
    w0[0] = pkrtz(y2[0][0], y2[0][1]); w0[1] = pkrtz(y2[0][2], y2[0][3]);
    w0[2] = pkrtz(y2[1][0], y2[1][1]); w0[3] = pkrtz(y2[1][2], y2[1][3]);
    w1[0] = pkrtz(y2[2][0], y2[2][1]); w1[1] = pkrtz(y2[2][2], y2[2][3]);
    w1[2] = pkrtz(y2[3][0], y2[3][1]); w1[3] = pkrtz(y2[3][2], y2[3][3]);
    buf[myKey] = w0;
    buf[myKey ^ 1] = w1;
  }
  __syncthreads();

  if (v < 20) {
    const int n = c_srows[v];
    const unsigned int cp = packG[sg * NPG + n];
    const int ccount = (int)(cp & 0xffffu);
    const int cstart = (int)(cp >> 16);
    const float cinv = rsqrtf((float)ccount + 1.0f);
    const int ckey = (n << 1) | (n & 1);
    fvec4 s2[4];
#pragma unroll
    for (int q = 0; q < 4; ++q) s2[q] = fvec4{0.f, 0.f, 0.f, 0.f};
    {
      const ivec4 w0 = buf[ckey], w1 = buf[ckey ^ 1];
      ACCQ(s2[0], s2[1], w0) ACCQ(s2[2], s2[3], w1)
    }
    for (int e = cstart; e < cstart + ccount; ++e) {
      const int la = sids[e];
      const int Ka = (la << 1) | (la & 1);
      const ivec4 w0 = buf[Ka], w1 = buf[Ka ^ 1];
      ACCQ(s2[0], s2[1], w0) ACCQ(s2[2], s2[3], w1)
    }
    const int hb = (side * BB + g) * 20;
    const fvec4* gb2v = reinterpret_cast<const fvec4*>(gb2);
    fvec4* hp = reinterpret_cast<fvec4*>(hs2 + ((size_t)hb + v) * 16);
#pragma unroll
    for (int q = 0; q < 4; ++q) hp[q] = s2[q] * cinv + gb2v[q];
  }
}

// ---------------- head: sampled sim -> bilinear 10x10 -> conv3x3(1->8) -> MLP -> sigmoid ----------------
__global__ __launch_bounds__(256) void k_head(const float* __restrict__ hs0, const float* __restrict__ hs1,
                                              const float* __restrict__ hs2,
                                              const float* __restrict__ cw0, const float* __restrict__ cb0,
                                              const float* __restrict__ cw1, const float* __restrict__ cb1,
                                              const float* __restrict__ cw2, const float* __restrict__ cb2,
                                              const float* __restrict__ mw0, const float* __restrict__ mb0,
                                              const float* __restrict__ mw1, const float* __restrict__ mb1,
                                              const float* __restrict__ mw2, const float* __restrict__ mb2,
                                              const float* __restrict__ mw3, const float* __restrict__ mb3,
                                              const float* __restrict__ mw4, const float* __restrict__ mb4,
                                              const float* __restrict__ sw, const float* __restrict__ sb,
                                              float* __restrict__ out) {
  __shared__ float hi[2240];  // 20*64 + 20*32 + 20*16
  __shared__ float hj[2240];
  __shared__ float sim[400];
  __shared__ float simr[100];
  __shared__ float feat[2400];
  __shared__ float red[256];
  __shared__ float mbuf[60];
  const int b = blockIdx.x, t = threadIdx.x;

  for (int k = t; k < 1280; k += 256) {
    hi[k] = hs0[(size_t)(0 * BB + b) * 1280 + k];
    hj[k] = hs0[(size_t)(1 * BB + b) * 1280 + k];
  }
  for (int k = t; k < 640; k += 256) {
    hi[1280 + k] = hs1[(size_t)(0 * BB + b) * 640 + k];
    hj[1280 + k] = hs1[(size_t)(1 * BB + b) * 640 + k];
  }
  for (int k = t; k < 320; k += 256) {
    hi[1920 + k] = hs2[(size_t)(0 * BB + b) * 320 + k];
    hj[1920 + k] = hs2[(size_t)(1 * BB + b) * 320 + k];
  }
  __syncthreads();

  const int Fs[3] = {64, 32, 16};
  const int HOFF[3] = {0, 1280, 1920};
  const float* CW[3] = {cw0, cw1, cw2};
  const float* CB[3] = {cb0, cb1, cb2};

  for (int li = 0; li < 3; ++li) {
    const int F = Fs[li];
    const float* Hi = hi + HOFF[li];
    const float* Hj = hj + HOFF[li];
    for (int p = t; p < 400; p += 256) {
      int r = p / 20, cq = p % 20;
      float a = 0.0f;
      for (int d = 0; d < F; ++d) a += Hi[r * F + d] * Hj[cq * F + d];
      sim[p] = a;
    }
    __syncthreads();
    if (t < 100) {
      int oy = t / 10, ox = t % 10;
      float cy = (oy + 0.5f) * (512.0f / 10.0f) - 0.5f;
      float cx = (ox + 0.5f) * (512.0f / 10.0f) - 0.5f;
      float fy = cy - floorf(cy);
      float fx = cx - floorf(cx);
      int r0 = 2 * oy, c0 = 2 * ox;
      float s00 = sim[r0 * 20 + c0], s01 = sim[r0 * 20 + c0 + 1];
      float s10 = sim[(r0 + 1) * 20 + c0], s11 = sim[(r0 + 1) * 20 + c0 + 1];
      simr[t] = (1.0f - fy) * ((1.0f - fx) * s00 + fx * s01) + fy * ((1.0f - fx) * s10 + fx * s11);
    }
    __syncthreads();
    const float* cw = CW[li];
    const float* cb = CB[li];
    for (int idx = t; idx < 800; idx += 256) {
      int cch = idx / 100, rem = idx % 100, y = rem / 10, x = rem % 10;
      float a = cb[cch];
#pragma unroll
      for (int ky = 0; ky < 3; ++ky) {
#pragma unroll
        for (int kx = 0; kx < 3; ++kx) {
          int iy = y + ky - 1, ix = x + kx - 1;
          if (iy >= 0 && iy < 10 && ix >= 0 && ix < 10)
            a += cw[cch * 9 + ky * 3 + kx] * simr[iy * 10 + ix];
        }
      }
      feat[li * 800 + idx] = fmaxf(a, 0.0f);
    }
    __syncthreads();
  }

  // MLP0: 2400 -> 32, 8 partial sums per output
  {
    int f = t & 31, part = t >> 5;
    float a = 0.0f;
    int k0 = part * 300;
    for (int k = k0; k < k0 + 300; ++k) a += feat[k] * mw0[k * 32 + f];
    red[t] = a;
    __syncthreads();
    if (t < 32) {
      float s = mb0[t];
#pragma unroll
      for (int p = 0; p < 8; ++p) s += red[p * 32 + t];
      mbuf[t] = fmaxf(s, 0.0f);
    }
    __syncthreads();
  }
  if (t < 16) {
    float s = mb1[t];
    for (int k = 0; k < 32; ++k) s += mbuf[k] * mw1[k * 16 + t];
    mbuf[32 + t] = fmaxf(s, 0.0f);
  }
  __syncthreads();
  if (t < 8) {
    float s = mb2[t];
    for (int k = 0; k < 16; ++k) s += mbuf[32 + k] * mw2[k * 8 + t];
    mbuf[48 + t] = fmaxf(s, 0.0f);
  }
  __syncthreads();
  if (t < 4) {
    float s = mb3[t];
    for (int k = 0; k < 8; ++k) s += mbuf[48 + k] * mw3[k * 4 + t];
    mbuf[56 + t] = fmaxf(s, 0.0f);
  }
  __syncthreads();
  if (t == 0) {
    float s = mb4[0];
    for (int k = 0; k < 4; ++k) s += mbuf[56 + k] * mw4[k];
    s = fmaxf(s, 0.0f);
    float z = s * sw[0] + sb[0];
    out[b] = 1.0f / (1.0f + expf(-z));
  }
}

extern "C" void kernel_launch(void* const* d_in, const int* in_sizes, int n_in,
                              void* d_out, int out_size, void* d_ws, size_t ws_size,
                              hipStream_t stream) {
  (void)in_sizes; (void)n_in; (void)out_size; (void)ws_size;
  const float* x_i = (const float*)d_in[0];
  const float* x_j = (const float*)d_in[1];
  const float* gw0 = (const float*)d_in[2];
  const float* gb0 = (const float*)d_in[3];
  const float* gw1 = (const float*)d_in[4];
  const float* gb1 = (const float*)d_in[5];
  const float* gw2 = (const float*)d_in[6];
  const float* gb2 = (const float*)d_in[7];
  const float* cw0 = (const float*)d_in[8];
  const float* cb0 = (const float*)d_in[9];
  const float* cw1 = (const float*)d_in[10];
  const float* cb1 = (const float*)d_in[11];
  const float* cw2 = (const float*)d_in[12];
  const float* cb2 = (const float*)d_in[13];
  const float* mw0 = (const float*)d_in[14];
  const float* mb0 = (const float*)d_in[15];
  const float* mw1 = (const float*)d_in[16];
  const float* mb1 = (const float*)d_in[17];
  const float* mw2 = (const float*)d_in[18];
  const float* mb2 = (const float*)d_in[19];
  const float* mw3 = (const float*)d_in[20];
  const float* mb3 = (const float*)d_in[21];
  const float* mw4 = (const float*)d_in[22];
  const float* mb4 = (const float*)d_in[23];
  const float* scw = (const float*)d_in[24];
  const float* scb = (const float*)d_in[25];
  const int* ei = (const int*)d_in[26];
  const int* ej = (const int*)d_in[27];
  float* out = (float*)d_out;

  char* p = (char*)d_ws;
  auto take = [&](size_t bytes) {
    char* r = p;
    p += (bytes + 255) & ~(size_t)255;
    return r;
  };
  float* hs0 = (float*)take((size_t)2 * BB * 20 * 64 * 4);
  float* hs1 = (float*)take((size_t)2 * BB * 20 * 32 * 4);
  float* hs2 = (float*)take((size_t)2 * BB * 20 * 16 * 4);
  unsigned short* sidsG = (unsigned short*)take((size_t)2 * BB * EPG * 2);
  unsigned int* packG = (unsigned int*)take((size_t)2 * BB * NPG * 4);
  unsigned int* y1G = (unsigned int*)take((size_t)2 * BB * 2 * NPG * 16 * 4);
  unsigned int* y2G = (unsigned int*)take((size_t)2 * BB * 2 * NPG * 8 * 4);

  kP<<<2 * BB, 512, 0, stream>>>(ei, ej, sidsG, packG);
  kA<<<2 * BB * 2, 512, 0, stream>>>(x_i, x_j, gw0, gb0, gw1,
                                     sidsG, packG, hs0, y1G);
  kB<<<2 * BB * 2, 512, 0, stream>>>(gb1, gw2, sidsG, packG, y1G, hs1, y2G);
  kC<<<2 * BB, 512, 0, stream>>>(gb2, sidsG, packG, y2G, hs2);
  k_head<<<BB, 256, 0, stream>>>(hs0, hs1, hs2, cw0, cb0, cw1, cb1, cw2, cb2,
                                 mw0, mb0, mw1, mb1, mw2, mb2, mw3, mb3, mw4, mb4,
                                 scw, scb, out);
}

// Round 23
// 121.097 us; speedup vs baseline: 1.0255x; 1.0255x over previous
//
#include <hip/hip_runtime.h>
#include <hip/hip_fp16.h>

typedef float fvec4 __attribute__((ext_vector_type(4)));
typedef int ivec4 __attribute__((ext_vector_type(4)));

#define NN 65536      // total nodes per side (B*NPG)
#define EE 1048576    // edges per side (B*NPG*DEG)
#define BB 128
#define NPG 512
#define EPG 8192      // edges per graph (NPG*DEG)

__device__ __forceinline__ int pkrtz(float a, float b) {
  union { __half2 h; int i; } u; u.h = __floats2half2_rn(a, b); return u.i;
}
__device__ __forceinline__ float2 up2(int v) {
  union { int i; __half2 h; } u; u.i = v; return __half22float2(u.h);
}

// accumulate one 16B quad (8 f16) into two fvec4 f32 partial sums
#define ACCQ(SA, SB, w) { float2 f_; \
  f_ = up2((w)[0]); (SA)[0] += f_.x; (SA)[1] += f_.y; \
  f_ = up2((w)[1]); (SA)[2] += f_.x; (SA)[3] += f_.y; \
  f_ = up2((w)[2]); (SB)[0] += f_.x; (SB)[1] += f_.y; \
  f_ = up2((w)[3]); (SB)[2] += f_.x; (SB)[3] += f_.y; }

__device__ __forceinline__ int slot_of(int node) {
  constexpr int srows[20] = {25, 26, 76, 77, 127, 128, 178, 179, 229, 230,
                             281, 282, 332, 333, 383, 384, 434, 435, 485, 486};
  int slot = -1;
#pragma unroll
  for (int i = 0; i < 20; ++i)
    if (node == srows[i]) slot = i;
  return slot;
}
__constant__ int c_srows[20] = {25, 26, 76, 77, 127, 128, 178, 179, 229, 230,
                                281, 282, 332, 333, 383, 384, 434, 435, 485, 486};

// ================= kA: per (side,graph,half): in-block CSR + L0 half + y1 partial =================
// LDS 48.2KB -> 3 blocks/CU (24 waves/CU). Prep arrays (dsts/cnt/posb) alias buf and die
// before message publish. start/count kept in registers across the aliasing boundary.
__global__ __launch_bounds__(512)
void kA(const float* __restrict__ x_i, const float* __restrict__ x_j,
        const float* __restrict__ gw0, const float* __restrict__ gb0,
        const float* __restrict__ gw1,
        const int* __restrict__ ei, const int* __restrict__ ej,
        unsigned short* __restrict__ sidsG, unsigned int* __restrict__ packG,
        float* __restrict__ hs0, unsigned int* __restrict__ y1G) {
  __shared__ ivec4 buf[NPG * 4];          // 32 KB f16 msg rows; prep aliases below
  __shared__ unsigned short sids[EPG];    // 16 KB
  __shared__ int wsum[8];
  unsigned short* const dsts = reinterpret_cast<unsigned short*>(buf);                   // 16 KB
  int* const cnt = reinterpret_cast<int*>(reinterpret_cast<char*>(buf) + 16384);         // 2 KB
  int* const posb = reinterpret_cast<int*>(reinterpret_cast<char*>(buf) + 18432);        // 2 KB

  const int bid = blockIdx.x;
  const int half = bid & 1;
  const int sg = bid >> 1;
  const int side = sg >> 7, g = sg & 127;
  const float* __restrict__ x = side ? x_j : x_i;
  const int* __restrict__ eidx = side ? ej : ei;
  const int v = threadIdx.x;
  const int base = g * NPG, ebase = g * EPG;

  // ---- degree count (into aliased cnt) ----
  cnt[v] = 0;
  __syncthreads();
  for (int k = v; k < EPG; k += 512) {
    int d = eidx[EE + ebase + k] - base;
    dsts[k] = (unsigned short)d;
    atomicAdd(&cnt[d], 1);
  }
  __syncthreads();

  // ---- exclusive scan over 512 counts ----
  const int count = cnt[v];
  int xa = count;
  const int lane = v & 63;
#pragma unroll
  for (int d = 1; d < 64; d <<= 1) {
    int y = __shfl_up(xa, d, 64);
    if (lane >= d) xa += y;
  }
  const int wid = v >> 6;
  if (lane == 63) wsum[wid] = xa;
  __syncthreads();
  if (v == 0) {
    int a = 0;
#pragma unroll
    for (int i = 0; i < 8; ++i) { int tv = wsum[i]; wsum[i] = a; a += tv; }
  }
  __syncthreads();
  const int start = xa - count + wsum[wid];  // kept in reg (posb will be clobbered)
  posb[v] = start;
  if (half == 0) packG[sg * NPG + v] = ((unsigned int)start << 16) | (unsigned int)count;
  __syncthreads();

  // ---- CSR fill (bucket by dst), raw ids ----
  for (int k = v; k < EPG; k += 512) {
    int lv = eidx[ebase + k] - base;
    int p = atomicAdd(&posb[dsts[k]], 1);
    sids[p] = (unsigned short)lv;
  }

  // ---- L0 half-GEMM: a0 = x_row @ W0[:, half*32 : half*32+32] (registers only) ----
  fvec4 a0[8];
#pragma unroll
  for (int q = 0; q < 8; ++q) a0[q] = fvec4{0.f, 0.f, 0.f, 0.f};
  {
    const fvec4* xv = reinterpret_cast<const fvec4*>(x + (size_t)(base + v) * 64);
    const float* w0h = gw0 + half * 32;
#pragma unroll 1
    for (int k16 = 0; k16 < 4; ++k16) {
      fvec4 xq[4];
#pragma unroll
      for (int u = 0; u < 4; ++u) xq[u] = xv[4 * k16 + u];
#pragma unroll
      for (int u = 0; u < 4; ++u) {
#pragma unroll
        for (int j = 0; j < 4; ++j) {
          const float xk = xq[u][j];
          const fvec4* wr = reinterpret_cast<const fvec4*>(w0h + (size_t)(16 * k16 + 4 * u + j) * 64);
#pragma unroll
          for (int q = 0; q < 8; ++q) a0[q] += xk * wr[q];
        }
      }
    }
  }
  __syncthreads();  // fill complete everywhere; dsts/cnt/posb dead -> buf reusable

  // ---- export CSR once (half 0) for kB/kC ----
  if (half == 0) {
    const int* srcI = reinterpret_cast<const int*>(sids);
    int* dstI = reinterpret_cast<int*>(sidsG + (size_t)sg * EPG);
    for (int k = v; k < EPG / 2; k += 512) dstI[k] = srcI[k];
  }

  // ---- publish own messages (f16, swizzled) ----
  const float inv_v = rsqrtf((float)count + 1.0f);
  const int myKey = (v << 2) | ((v >> 1) & 3);
  fvec4 s[8];
#pragma unroll
  for (int q = 0; q < 8; ++q) s[q] = a0[q] * inv_v;
#pragma unroll
  for (int q_ = 0; q_ < 4; ++q_) {
    ivec4 w_;
    w_[0] = pkrtz(s[2 * q_][0], s[2 * q_][1]);
    w_[1] = pkrtz(s[2 * q_][2], s[2 * q_][3]);
    w_[2] = pkrtz(s[2 * q_ + 1][0], s[2 * q_ + 1][1]);
    w_[3] = pkrtz(s[2 * q_ + 1][2], s[2 * q_ + 1][3]);
    buf[myKey ^ q_] = w_;
  }
  __syncthreads();

  // ---- gather 32 feats (unroll x2, keys from raw ids) ----
  {
    int e = start;
    const int end = start + count;
    for (; e + 2 <= end; e += 2) {
      const int la = sids[e], lb = sids[e + 1];
      const int Ka = (la << 2) | ((la >> 1) & 3);
      const int Kb = (lb << 2) | ((lb >> 1) & 3);
      const ivec4 a0_ = buf[Ka], a1_ = buf[Ka ^ 1], a2_ = buf[Ka ^ 2], a3_ = buf[Ka ^ 3];
      const ivec4 b0_ = buf[Kb], b1_ = buf[Kb ^ 1], b2_ = buf[Kb ^ 2], b3_ = buf[Kb ^ 3];
      ACCQ(s[0], s[1], a0_) ACCQ(s[2], s[3], a1_) ACCQ(s[4], s[5], a2_) ACCQ(s[6], s[7], a3_)
      ACCQ(s[0], s[1], b0_) ACCQ(s[2], s[3], b1_) ACCQ(s[4], s[5], b2_) ACCQ(s[6], s[7], b3_)
    }
    if (e < end) {
      const int la = sids[e];
      const int Ka = (la << 2) | ((la >> 1) & 3);
      const ivec4 a0_ = buf[Ka], a1_ = buf[Ka ^ 1], a2_ = buf[Ka ^ 2], a3_ = buf[Ka ^ 3];
      ACCQ(s[0], s[1], a0_) ACCQ(s[2], s[3], a1_) ACCQ(s[4], s[5], a2_) ACCQ(s[6], s[7], a3_)
    }
  }

  // ---- epilogue: h0_half = relu(s*inv + b); hs0 slice; fold y1P = h0_half @ W1[half rows] ----
  const int slot = slot_of(v);
  const int hb = (side * BB + g) * 20;
  fvec4 y1P[8];
#pragma unroll
  for (int p = 0; p < 8; ++p) y1P[p] = fvec4{0.f, 0.f, 0.f, 0.f};
  {
    const fvec4* gb0v = reinterpret_cast<const fvec4*>(gb0 + half * 32);
    fvec4* hp = reinterpret_cast<fvec4*>(hs0 + ((size_t)hb + slot) * 64 + half * 32);
#pragma unroll
    for (int q = 0; q < 8; ++q) {
      fvec4 o = s[q] * inv_v + gb0v[q];
#pragma unroll
      for (int j = 0; j < 4; ++j) o[j] = fmaxf(o[j], 0.f);
      if (slot >= 0) hp[q] = o;
#pragma unroll
      for (int j = 0; j < 4; ++j) {
        const float hf = o[j];
        const fvec4* wr = reinterpret_cast<const fvec4*>(gw1 + (size_t)(half * 32 + q * 4 + j) * 32);
#pragma unroll
        for (int p = 0; p < 8; ++p) y1P[p] += hf * wr[p];
      }
    }
  }
  {
    unsigned int* yp = y1G + ((size_t)(sg * 2 + half) * NPG + v) * 16;
#pragma unroll
    for (int w = 0; w < 16; ++w)
      yp[w] = (unsigned int)pkrtz(y1P[w >> 1][(w & 1) * 2], y1P[w >> 1][(w & 1) * 2 + 1]);
  }
}

// ================= kB: per (side,graph,half): L1 (16-feat slice) + y2 partial =================
__global__ __launch_bounds__(512)
void kB(const float* __restrict__ gb1, const float* __restrict__ gw2,
        const unsigned short* __restrict__ sidsG, const unsigned int* __restrict__ packG,
        const unsigned int* __restrict__ y1G,
        float* __restrict__ hs1, unsigned int* __restrict__ y2G) {
  __shared__ ivec4 buf[NPG * 2];          // 16 KB: msg rows of 2 quads
  __shared__ unsigned short sids[EPG];    // 16 KB
  const int bid = blockIdx.x;
  const int half = bid & 1;
  const int sg = bid >> 1;
  const int side = sg >> 7, g = sg & 127;
  const int v = threadIdx.x;

  {
    const int* srcI = reinterpret_cast<const int*>(sidsG + (size_t)sg * EPG);
    int* dstI = reinterpret_cast<int*>(sids);
    for (int k = v; k < EPG / 2; k += 512) dstI[k] = srcI[k];
  }
  const unsigned int pack = packG[sg * NPG + v];
  const int count = (int)(pack & 0xffffu);
  const int nstart = (int)(pack >> 16);
  const float inv_v = rsqrtf((float)count + 1.0f);

  // ---- y1 slice = sum of both halves' partials (16 f32) ----
  fvec4 s1[4];
  {
    const unsigned int* p0 = y1G + ((size_t)(sg * 2 + 0) * NPG + v) * 16 + half * 8;
    const unsigned int* p1 = y1G + ((size_t)(sg * 2 + 1) * NPG + v) * 16 + half * 8;
#pragma unroll
    for (int w = 0; w < 8; ++w) {
      float2 fa = up2((int)p0[w]);
      float2 fb = up2((int)p1[w]);
      s1[w >> 1][(w & 1) * 2] = (fa.x + fb.x) * inv_v;
      s1[w >> 1][(w & 1) * 2 + 1] = (fa.y + fb.y) * inv_v;
    }
  }
  // ---- publish 16 f16 (2 quads), key1 = (v<<1)|(v&1) ----
  const int myKey = (v << 1) | (v & 1);
  {
    ivec4 w0, w1;
    w0[0] = pkrtz(s1[0][0], s1[0][1]); w0[1] = pkrtz(s1[0][2], s1[0][3]);
    w0[2] = pkrtz(s1[1][0], s1[1][1]); w0[3] = pkrtz(s1[1][2], s1[1][3]);
    w1[0] = pkrtz(s1[2][0], s1[2][1]); w1[1] = pkrtz(s1[2][2], s1[2][3]);
    w1[2] = pkrtz(s1[3][0], s1[3][1]); w1[3] = pkrtz(s1[3][2], s1[3][3]);
    buf[myKey] = w0;
    buf[myKey ^ 1] = w1;
  }
  __syncthreads();

  // ---- gather 16 feats (unroll x2) ----
  {
    int e = nstart;
    const int end = nstart + count;
    for (; e + 2 <= end; e += 2) {
      const int la = sids[e], lb = sids[e + 1];
      const int Ka = (la << 1) | (la & 1), Kb = (lb << 1) | (lb & 1);
      const ivec4 a0_ = buf[Ka], a1_ = buf[Ka ^ 1];
      const ivec4 b0_ = buf[Kb], b1_ = buf[Kb ^ 1];
      ACCQ(s1[0], s1[1], a0_) ACCQ(s1[2], s1[3], a1_)
      ACCQ(s1[0], s1[1], b0_) ACCQ(s1[2], s1[3], b1_)
    }
    if (e < end) {
      const int la = sids[e];
      const int Ka = (la << 1) | (la & 1);
      const ivec4 a0_ = buf[Ka], a1_ = buf[Ka ^ 1];
      ACCQ(s1[0], s1[1], a0_) ACCQ(s1[2], s1[3], a1_)
    }
  }

  // ---- epilogue: h1_half = relu(s1*inv + b); hs1 slice; fold y2P = h1_half @ W2[half rows] ----
  const int slot = slot_of(v);
  const int hb = (side * BB + g) * 20;
  fvec4 y2P[4];
#pragma unroll
  for (int p = 0; p < 4; ++p) y2P[p] = fvec4{0.f, 0.f, 0.f, 0.f};
  {
    const fvec4* gb1v = reinterpret_cast<const fvec4*>(gb1 + half * 16);
    fvec4* hp = reinterpret_cast<fvec4*>(hs1 + ((size_t)hb + slot) * 32 + half * 16);
#pragma unroll
    for (int q = 0; q < 4; ++q) {
      fvec4 o = s1[q] * inv_v + gb1v[q];
#pragma unroll
      for (int j = 0; j < 4; ++j) o[j] = fmaxf(o[j], 0.f);
      if (slot >= 0) hp[q] = o;
#pragma unroll
      for (int j = 0; j < 4; ++j) {
        const float hf = o[j];
        const fvec4* wr = reinterpret_cast<const fvec4*>(gw2 + (size_t)(half * 16 + q * 4 + j) * 16);
#pragma unroll
        for (int p = 0; p < 4; ++p) y2P[p] += hf * wr[p];
      }
    }
  }
  {
    unsigned int* yp = y2G + ((size_t)(sg * 2 + half) * NPG + v) * 8;
#pragma unroll
    for (int w = 0; w < 8; ++w)
      yp[w] = (unsigned int)pkrtz(y2P[w >> 1][(w & 1) * 2], y2P[w >> 1][(w & 1) * 2 + 1]);
  }
}

// ================= kC: per (side,graph): L2 gather for sampled rows only =================
__global__ __launch_bounds__(512)
void kC(const float* __restrict__ gb2,
        const unsigned short* __restrict__ sidsG, const unsigned int* __restrict__ packG,
        const unsigned int* __restrict__ y2G, float* __restrict__ hs2) {
  __shared__ ivec4 buf[NPG * 2];          // 16 KB
  __shared__ unsigned short sids[EPG];    // 16 KB
  const int sg = blockIdx.x;
  const int side = sg >> 7, g = sg & 127;
  const int v = threadIdx.x;

  {
    const int* srcI = reinterpret_cast<const int*>(sidsG + (size_t)sg * EPG);
    int* dstI = reinterpret_cast<int*>(sids);
    for (int k = v; k < EPG / 2; k += 512) dstI[k] = srcI[k];
  }
  const unsigned int pack = packG[sg * NPG + v];
  const int count = (int)(pack & 0xffffu);
  const float inv_v = rsqrtf((float)count + 1.0f);

  // y2 full = sum of both halves' partials; publish msg = y2*inv (16 f16)
  const int myKey = (v << 1) | (v & 1);
  {
    const unsigned int* p0 = y2G + ((size_t)(sg * 2 + 0) * NPG + v) * 8;
    const unsigned int* p1 = y2G + ((size_t)(sg * 2 + 1) * NPG + v) * 8;
    fvec4 y2[4];
#pragma unroll
    for (int w = 0; w < 8; ++w) {
      float2 fa = up2((int)p0[w]);
      float2 fb = up2((int)p1[w]);
      y2[w >> 1][(w & 1) * 2] = (fa.x + fb.x) * inv_v;
      y2[w >> 1][(w & 1) * 2 + 1] = (fa.y + fb.y) * inv_v;
    }
    ivec4 w0, w1;
    w0[0] = pkrtz(y2[0][0], y2[0][1]); w0[1] = pkrtz(y2[0][2], y2[0][3]);
    w0[2] = pkrtz(y2[1][0], y2[1][1]); w0[3] = pkrtz(y2[1][2], y2[1][3]);
    w1[0] = pkrtz(y2[2][0], y2[2][1]); w1[1] = pkrtz(y2[2][2], y2[2][3]);
    w1[2] = pkrtz(y2[3][0], y2[3][1]); w1[3] = pkrtz(y2[3][2], y2[3][3]);
    buf[myKey] = w0;
    buf[myKey ^ 1] = w1;
  }
  __syncthreads();

  if (v < 20) {
    const int n = c_srows[v];
    const unsigned int cp = packG[sg * NPG + n];
    const int ccount = (int)(cp & 0xffffu);
    const int cstart = (int)(cp >> 16);
    const float cinv = rsqrtf((float)ccount + 1.0f);
    const int ckey = (n << 1) | (n & 1);
    fvec4 s2[4];
#pragma unroll
    for (int q = 0; q < 4; ++q) s2[q] = fvec4{0.f, 0.f, 0.f, 0.f};
    {
      const ivec4 w0 = buf[ckey], w1 = buf[ckey ^ 1];
      ACCQ(s2[0], s2[1], w0) ACCQ(s2[2], s2[3], w1)
    }
    for (int e = cstart; e < cstart + ccount; ++e) {
      const int la = sids[e];
      const int Ka = (la << 1) | (la & 1);
      const ivec4 w0 = buf[Ka], w1 = buf[Ka ^ 1];
      ACCQ(s2[0], s2[1], w0) ACCQ(s2[2], s2[3], w1)
    }
    const int hb = (side * BB + g) * 20;
    const fvec4* gb2v = reinterpret_cast<const fvec4*>(gb2);
    fvec4* hp = reinterpret_cast<fvec4*>(hs2 + ((size_t)hb + v) * 16);
#pragma unroll
    for (int q = 0; q < 4; ++q) hp[q] = s2[q] * cinv + gb2v[q];
  }
}

// ---------------- head: sampled sim -> bilinear 10x10 -> conv3x3(1->8) -> MLP -> sigmoid ----------------
__global__ __launch_bounds__(256) void k_head(const float* __restrict__ hs0, const float* __restrict__ hs1,
                                              const float* __restrict__ hs2,
                                              const float* __restrict__ cw0, const float* __restrict__ cb0,
                                              const float* __restrict__ cw1, const float* __restrict__ cb1,
                                              const float* __restrict__ cw2, const float* __restrict__ cb2,
                                              const float* __restrict__ mw0, const float* __restrict__ mb0,
                                              const float* __restrict__ mw1, const float* __restrict__ mb1,
                                              const float* __restrict__ mw2, const float* __restrict__ mb2,
                                              const float* __restrict__ mw3, const float* __restrict__ mb3,
                                              const float* __restrict__ mw4, const float* __restrict__ mb4,
                                              const float* __restrict__ sw, const float* __restrict__ sb,
                                              float* __restrict__ out) {
  __shared__ float hi[2240];  // 20*64 + 20*32 + 20*16
  __shared__ float hj[2240];
  __shared__ float sim[400];
  __shared__ float simr[100];
  __shared__ float feat[2400];
  __shared__ float red[256];
  __shared__ float mbuf[60];
  const int b = blockIdx.x, t = threadIdx.x;

  for (int k = t; k < 1280; k += 256) {
    hi[k] = hs0[(size_t)(0 * BB + b) * 1280 + k];
    hj[k] = hs0[(size_t)(1 * BB + b) * 1280 + k];
  }
  for (int k = t; k < 640; k += 256) {
    hi[1280 + k] = hs1[(size_t)(0 * BB + b) * 640 + k];
    hj[1280 + k] = hs1[(size_t)(1 * BB + b) * 640 + k];
  }
  for (int k = t; k < 320; k += 256) {
    hi[1920 + k] = hs2[(size_t)(0 * BB + b) * 320 + k];
    hj[1920 + k] = hs2[(size_t)(1 * BB + b) * 320 + k];
  }
  __syncthreads();

  const int Fs[3] = {64, 32, 16};
  const int HOFF[3] = {0, 1280, 1920};
  const float* CW[3] = {cw0, cw1, cw2};
  const float* CB[3] = {cb0, cb1, cb2};

  for (int li = 0; li < 3; ++li) {
    const int F = Fs[li];
    const float* Hi = hi + HOFF[li];
    const float* Hj = hj + HOFF[li];
    for (int p = t; p < 400; p += 256) {
      int r = p / 20, cq = p % 20;
      float a = 0.0f;
      for (int d = 0; d < F; ++d) a += Hi[r * F + d] * Hj[cq * F + d];
      sim[p] = a;
    }
    __syncthreads();
    if (t < 100) {
      int oy = t / 10, ox = t % 10;
      float cy = (oy + 0.5f) * (512.0f / 10.0f) - 0.5f;
      float cx = (ox + 0.5f) * (512.0f / 10.0f) - 0.5f;
      float fy = cy - floorf(cy);
      float fx = cx - floorf(cx);
      int r0 = 2 * oy, c0 = 2 * ox;
      float s00 = sim[r0 * 20 + c0], s01 = sim[r0 * 20 + c0 + 1];
      float s10 = sim[(r0 + 1) * 20 + c0], s11 = sim[(r0 + 1) * 20 + c0 + 1];
      simr[t] = (1.0f - fy) * ((1.0f - fx) * s00 + fx * s01) + fy * ((1.0f - fx) * s10 + fx * s11);
    }
    __syncthreads();
    const float* cw = CW[li];
    const float* cb = CB[li];
    for (int idx = t; idx < 800; idx += 256) {
      int cch = idx / 100, rem = idx % 100, y = rem / 10, x = rem % 10;
      float a = cb[cch];
#pragma unroll
      for (int ky = 0; ky < 3; ++ky) {
#pragma unroll
        for (int kx = 0; kx < 3; ++kx) {
          int iy = y + ky - 1, ix = x + kx - 1;
          if (iy >= 0 && iy < 10 && ix >= 0 && ix < 10)
            a += cw[cch * 9 + ky * 3 + kx] * simr[iy * 10 + ix];
        }
      }
      feat[li * 800 + idx] = fmaxf(a, 0.0f);
    }
    __syncthreads();
  }

  // MLP0: 2400 -> 32, 8 partial sums per output
  {
    int f = t & 31, part = t >> 5;
    float a = 0.0f;
    int k0 = part * 300;
    for (int k = k0; k < k0 + 300; ++k) a += feat[k] * mw0[k * 32 + f];
    red[t] = a;
    __syncthreads();
    if (t < 32) {
      float s = mb0[t];
#pragma unroll
      for (int p = 0; p < 8; ++p) s += red[p * 32 + t];
      mbuf[t] = fmaxf(s, 0.0f);
    }
    __syncthreads();
  }
  if (t < 16) {
    float s = mb1[t];
    for (int k = 0; k < 32; ++k) s += mbuf[k] * mw1[k * 16 + t];
    mbuf[32 + t] = fmaxf(s, 0.0f);
  }
  __syncthreads();
  if (t < 8) {
    float s = mb2[t];
    for (int k = 0; k < 16; ++k) s += mbuf[32 + k] * mw2[k * 8 + t];
    mbuf[48 + t] = fmaxf(s, 0.0f);
  }
  __syncthreads();
  if (t < 4) {
    float s = mb3[t];
    for (int k = 0; k < 8; ++k) s += mbuf[48 + k] * mw3[k * 4 + t];
    mbuf[56 + t] = fmaxf(s, 0.0f);
  }
  __syncthreads();
  if (t == 0) {
    float s = mb4[0];
    for (int k = 0; k < 4; ++k) s += mbuf[56 + k] * mw4[k];
    s = fmaxf(s, 0.0f);
    float z = s * sw[0] + sb[0];
    out[b] = 1.0f / (1.0f + expf(-z));
  }
}

extern "C" void kernel_launch(void* const* d_in, const int* in_sizes, int n_in,
                              void* d_out, int out_size, void* d_ws, size_t ws_size,
                              hipStream_t stream) {
  (void)in_sizes; (void)n_in; (void)out_size; (void)ws_size;
  const float* x_i = (const float*)d_in[0];
  const float* x_j = (const float*)d_in[1];
  const float* gw0 = (const float*)d_in[2];
  const float* gb0 = (const float*)d_in[3];
  const float* gw1 = (const float*)d_in[4];
  const float* gb1 = (const float*)d_in[5];
  const float* gw2 = (const float*)d_in[6];
  const float* gb2 = (const float*)d_in[7];
  const float* cw0 = (const float*)d_in[8];
  const float* cb0 = (const float*)d_in[9];
  const float* cw1 = (const float*)d_in[10];
  const float* cb1 = (const float*)d_in[11];
  const float* cw2 = (const float*)d_in[12];
  const float* cb2 = (const float*)d_in[13];
  const float* mw0 = (const float*)d_in[14];
  const float* mb0 = (const float*)d_in[15];
  const float* mw1 = (const float*)d_in[16];
  const float* mb1 = (const float*)d_in[17];
  const float* mw2 = (const float*)d_in[18];
  const float* mb2 = (const float*)d_in[19];
  const float* mw3 = (const float*)d_in[20];
  const float* mb3 = (const float*)d_in[21];
  const float* mw4 = (const float*)d_in[22];
  const float* mb4 = (const float*)d_in[23];
  const float* scw = (const float*)d_in[24];
  const float* scb = (const float*)d_in[25];
  const int* ei = (const int*)d_in[26];
  const int* ej = (const int*)d_in[27];
  float* out = (float*)d_out;

  char* p = (char*)d_ws;
  auto take = [&](size_t bytes) {
    char* r = p;
    p += (bytes + 255) & ~(size_t)255;
    return r;
  };
  float* hs0 = (float*)take((size_t)2 * BB * 20 * 64 * 4);
  float* hs1 = (float*)take((size_t)2 * BB * 20 * 32 * 4);
  float* hs2 = (float*)take((size_t)2 * BB * 20 * 16 * 4);
  unsigned short* sidsG = (unsigned short*)take((size_t)2 * BB * EPG * 2);
  unsigned int* packG = (unsigned int*)take((size_t)2 * BB * NPG * 4);
  unsigned int* y1G = (unsigned int*)take((size_t)2 * BB * 2 * NPG * 16 * 4);
  unsigned int* y2G = (unsigned int*)take((size_t)2 * BB * 2 * NPG * 8 * 4);

  kA<<<2 * BB * 2, 512, 0, stream>>>(x_i, x_j, gw0, gb0, gw1, ei, ej,
                                     sidsG, packG, hs0, y1G);
  kB<<<2 * BB * 2, 512, 0, stream>>>(gb1, gw2, sidsG, packG, y1G, hs1, y2G);
  kC<<<2 * BB, 512, 0, stream>>>(gb2, sidsG, packG, y2G, hs2);
  k_head<<<BB, 256, 0, stream>>>(hs0, hs1, hs2, cw0, cb0, cw1, cb1, cw2, cb2,
                                 mw0, mb0, mw1, mb1, mw2, mb2, mw3, mb3, mw4, mb4,
                                 scw, scb, out);
}

// Round 24
// 119.247 us; speedup vs baseline: 1.0414x; 1.0155x over previous
//
#include <hip/hip_runtime.h>
#include <hip/hip_fp16.h>

typedef float fvec4 __attribute__((ext_vector_type(4)));
typedef int ivec4 __attribute__((ext_vector_type(4)));

#define NN 65536      // total nodes per side (B*NPG)
#define EE 1048576    // edges per side (B*NPG*DEG)
#define BB 128
#define NPG 512
#define EPG 8192      // edges per graph (NPG*DEG)

__device__ __forceinline__ int pkrtz(float a, float b) {
  union { __half2 h; int i; } u; u.h = __floats2half2_rn(a, b); return u.i;
}
__device__ __forceinline__ float2 up2(int v) {
  union { int i; __half2 h; } u; u.i = v; return __half22float2(u.h);
}
__device__ __forceinline__ __half2 h2(int v) {
  union { int i; __half2 h; } u; u.i = v; return u.h;
}

// packed-f16 accumulate: one 16B quad (8 f16) into 4 half2 accumulators (4 v_pk_add_f16)
#define ACCP(SP, w) { \
  (SP)[0] = __hadd2((SP)[0], h2((w)[0])); \
  (SP)[1] = __hadd2((SP)[1], h2((w)[1])); \
  (SP)[2] = __hadd2((SP)[2], h2((w)[2])); \
  (SP)[3] = __hadd2((SP)[3], h2((w)[3])); }

__device__ __forceinline__ int slot_of(int node) {
  constexpr int srows[20] = {25, 26, 76, 77, 127, 128, 178, 179, 229, 230,
                             281, 282, 332, 333, 383, 384, 434, 435, 485, 486};
  int slot = -1;
#pragma unroll
  for (int i = 0; i < 20; ++i)
    if (node == srows[i]) slot = i;
  return slot;
}
__constant__ int c_srows[20] = {25, 26, 76, 77, 127, 128, 178, 179, 229, 230,
                                281, 282, 332, 333, 383, 384, 434, 435, 485, 486};

// ================= kA: per (side,graph,half): in-block CSR + L0 half + y1 partial =================
// LDS ~48.5KB -> 3 blocks/CU. Prep arrays (dsts/cnt/posb) alias buf and die before publish.
// Gather accumulates in packed f16 (v_pk_add_f16), converted to f32 once after the loop.
__global__ __launch_bounds__(512)
void kA(const float* __restrict__ x_i, const float* __restrict__ x_j,
        const float* __restrict__ gw0, const float* __restrict__ gb0,
        const float* __restrict__ gw1,
        const int* __restrict__ ei, const int* __restrict__ ej,
        unsigned short* __restrict__ sidsG, unsigned int* __restrict__ packG,
        float* __restrict__ hs0, unsigned int* __restrict__ y1G) {
  __shared__ ivec4 buf[NPG * 4];          // 32 KB f16 msg rows; prep aliases below
  __shared__ unsigned short sids[EPG];    // 16 KB
  __shared__ int wsum[8];
  unsigned short* const dsts = reinterpret_cast<unsigned short*>(buf);                   // 16 KB
  int* const cnt = reinterpret_cast<int*>(reinterpret_cast<char*>(buf) + 16384);         // 2 KB
  int* const posb = reinterpret_cast<int*>(reinterpret_cast<char*>(buf) + 18432);        // 2 KB

  const int bid = blockIdx.x;
  const int half = bid & 1;
  const int sg = bid >> 1;
  const int side = sg >> 7, g = sg & 127;
  const float* __restrict__ x = side ? x_j : x_i;
  const int* __restrict__ eidx = side ? ej : ei;
  const int v = threadIdx.x;
  const int base = g * NPG, ebase = g * EPG;

  // ---- degree count (into aliased cnt) ----
  cnt[v] = 0;
  __syncthreads();
  for (int k = v; k < EPG; k += 512) {
    int d = eidx[EE + ebase + k] - base;
    dsts[k] = (unsigned short)d;
    atomicAdd(&cnt[d], 1);
  }
  __syncthreads();

  // ---- exclusive scan over 512 counts ----
  const int count = cnt[v];
  int xa = count;
  const int lane = v & 63;
#pragma unroll
  for (int d = 1; d < 64; d <<= 1) {
    int y = __shfl_up(xa, d, 64);
    if (lane >= d) xa += y;
  }
  const int wid = v >> 6;
  if (lane == 63) wsum[wid] = xa;
  __syncthreads();
  if (v == 0) {
    int a = 0;
#pragma unroll
    for (int i = 0; i < 8; ++i) { int tv = wsum[i]; wsum[i] = a; a += tv; }
  }
  __syncthreads();
  const int start = xa - count + wsum[wid];  // kept in reg (posb will be clobbered)
  posb[v] = start;
  if (half == 0) packG[sg * NPG + v] = ((unsigned int)start << 16) | (unsigned int)count;
  __syncthreads();

  // ---- CSR fill (bucket by dst), raw ids ----
  for (int k = v; k < EPG; k += 512) {
    int lv = eidx[ebase + k] - base;
    int p = atomicAdd(&posb[dsts[k]], 1);
    sids[p] = (unsigned short)lv;
  }

  // ---- L0 half-GEMM: a0 = x_row @ W0[:, half*32 : half*32+32] (registers only) ----
  fvec4 a0[8];
#pragma unroll
  for (int q = 0; q < 8; ++q) a0[q] = fvec4{0.f, 0.f, 0.f, 0.f};
  {
    const fvec4* xv = reinterpret_cast<const fvec4*>(x + (size_t)(base + v) * 64);
    const float* w0h = gw0 + half * 32;
#pragma unroll 1
    for (int k16 = 0; k16 < 4; ++k16) {
      fvec4 xq[4];
#pragma unroll
      for (int u = 0; u < 4; ++u) xq[u] = xv[4 * k16 + u];
#pragma unroll
      for (int u = 0; u < 4; ++u) {
#pragma unroll
        for (int j = 0; j < 4; ++j) {
          const float xk = xq[u][j];
          const fvec4* wr = reinterpret_cast<const fvec4*>(w0h + (size_t)(16 * k16 + 4 * u + j) * 64);
#pragma unroll
          for (int q = 0; q < 8; ++q) a0[q] += xk * wr[q];
        }
      }
    }
  }
  __syncthreads();  // fill complete everywhere; dsts/cnt/posb dead -> buf reusable

  // ---- export CSR once (half 0) for kB/kC ----
  if (half == 0) {
    const int* srcI = reinterpret_cast<const int*>(sids);
    int* dstI = reinterpret_cast<int*>(sidsG + (size_t)sg * EPG);
    for (int k = v; k < EPG / 2; k += 512) dstI[k] = srcI[k];
  }

  // ---- publish own messages (f16, swizzled); init packed accumulators with same bits ----
  const float inv_v = rsqrtf((float)count + 1.0f);
  const int myKey = (v << 2) | ((v >> 1) & 3);
  __half2 sp[16];
#pragma unroll
  for (int q_ = 0; q_ < 4; ++q_) {
    fvec4 m0 = a0[2 * q_] * inv_v;
    fvec4 m1 = a0[2 * q_ + 1] * inv_v;
    ivec4 w_;
    w_[0] = pkrtz(m0[0], m0[1]);
    w_[1] = pkrtz(m0[2], m0[3]);
    w_[2] = pkrtz(m1[0], m1[1]);
    w_[3] = pkrtz(m1[2], m1[3]);
    buf[myKey ^ q_] = w_;
    sp[4 * q_ + 0] = h2(w_[0]);
    sp[4 * q_ + 1] = h2(w_[1]);
    sp[4 * q_ + 2] = h2(w_[2]);
    sp[4 * q_ + 3] = h2(w_[3]);
  }
  __syncthreads();

  // ---- gather 32 feats (unroll x2, packed-f16 accumulation) ----
  {
    int e = start;
    const int end = start + count;
    for (; e + 2 <= end; e += 2) {
      const int la = sids[e], lb = sids[e + 1];
      const int Ka = (la << 2) | ((la >> 1) & 3);
      const int Kb = (lb << 2) | ((lb >> 1) & 3);
      const ivec4 a0_ = buf[Ka], a1_ = buf[Ka ^ 1], a2_ = buf[Ka ^ 2], a3_ = buf[Ka ^ 3];
      const ivec4 b0_ = buf[Kb], b1_ = buf[Kb ^ 1], b2_ = buf[Kb ^ 2], b3_ = buf[Kb ^ 3];
      ACCP(sp + 0, a0_) ACCP(sp + 4, a1_) ACCP(sp + 8, a2_) ACCP(sp + 12, a3_)
      ACCP(sp + 0, b0_) ACCP(sp + 4, b1_) ACCP(sp + 8, b2_) ACCP(sp + 12, b3_)
    }
    if (e < end) {
      const int la = sids[e];
      const int Ka = (la << 2) | ((la >> 1) & 3);
      const ivec4 a0_ = buf[Ka], a1_ = buf[Ka ^ 1], a2_ = buf[Ka ^ 2], a3_ = buf[Ka ^ 3];
      ACCP(sp + 0, a0_) ACCP(sp + 4, a1_) ACCP(sp + 8, a2_) ACCP(sp + 12, a3_)
    }
  }

  // ---- convert packed sums to f32 ----
  fvec4 s[8];
#pragma unroll
  for (int q_ = 0; q_ < 4; ++q_) {
    float2 f0 = __half22float2(sp[4 * q_ + 0]);
    float2 f1 = __half22float2(sp[4 * q_ + 1]);
    float2 f2 = __half22float2(sp[4 * q_ + 2]);
    float2 f3 = __half22float2(sp[4 * q_ + 3]);
    s[2 * q_][0] = f0.x; s[2 * q_][1] = f0.y; s[2 * q_][2] = f1.x; s[2 * q_][3] = f1.y;
    s[2 * q_ + 1][0] = f2.x; s[2 * q_ + 1][1] = f2.y; s[2 * q_ + 1][2] = f3.x; s[2 * q_ + 1][3] = f3.y;
  }

  // ---- epilogue: h0_half = relu(s*inv + b); hs0 slice; fold y1P = h0_half @ W1[half rows] ----
  const int slot = slot_of(v);
  const int hb = (side * BB + g) * 20;
  fvec4 y1P[8];
#pragma unroll
  for (int p = 0; p < 8; ++p) y1P[p] = fvec4{0.f, 0.f, 0.f, 0.f};
  {
    const fvec4* gb0v = reinterpret_cast<const fvec4*>(gb0 + half * 32);
    fvec4* hp = reinterpret_cast<fvec4*>(hs0 + ((size_t)hb + slot) * 64 + half * 32);
#pragma unroll
    for (int q = 0; q < 8; ++q) {
      fvec4 o = s[q] * inv_v + gb0v[q];
#pragma unroll
      for (int j = 0; j < 4; ++j) o[j] = fmaxf(o[j], 0.f);
      if (slot >= 0) hp[q] = o;
#pragma unroll
      for (int j = 0; j < 4; ++j) {
        const float hf = o[j];
        const fvec4* wr = reinterpret_cast<const fvec4*>(gw1 + (size_t)(half * 32 + q * 4 + j) * 32);
#pragma unroll
        for (int p = 0; p < 8; ++p) y1P[p] += hf * wr[p];
      }
    }
  }
  {
    unsigned int* yp = y1G + ((size_t)(sg * 2 + half) * NPG + v) * 16;
#pragma unroll
    for (int w = 0; w < 16; ++w)
      yp[w] = (unsigned int)pkrtz(y1P[w >> 1][(w & 1) * 2], y1P[w >> 1][(w & 1) * 2 + 1]);
  }
}

// ================= kB: per (side,graph,half): L1 (16-feat slice) + y2 partial =================
__global__ __launch_bounds__(512)
void kB(const float* __restrict__ gb1, const float* __restrict__ gw2,
        const unsigned short* __restrict__ sidsG, const unsigned int* __restrict__ packG,
        const unsigned int* __restrict__ y1G,
        float* __restrict__ hs1, unsigned int* __restrict__ y2G) {
  __shared__ ivec4 buf[NPG * 2];          // 16 KB: msg rows of 2 quads
  __shared__ unsigned short sids[EPG];    // 16 KB
  const int bid = blockIdx.x;
  const int half = bid & 1;
  const int sg = bid >> 1;
  const int side = sg >> 7, g = sg & 127;
  const int v = threadIdx.x;

  {
    const int* srcI = reinterpret_cast<const int*>(sidsG + (size_t)sg * EPG);
    int* dstI = reinterpret_cast<int*>(sids);
    for (int k = v; k < EPG / 2; k += 512) dstI[k] = srcI[k];
  }
  const unsigned int pack = packG[sg * NPG + v];
  const int count = (int)(pack & 0xffffu);
  const int nstart = (int)(pack >> 16);
  const float inv_v = rsqrtf((float)count + 1.0f);

  // ---- y1 slice = sum of both halves' partials (16 f32) ----
  fvec4 s1[4];
  {
    const unsigned int* p0 = y1G + ((size_t)(sg * 2 + 0) * NPG + v) * 16 + half * 8;
    const unsigned int* p1 = y1G + ((size_t)(sg * 2 + 1) * NPG + v) * 16 + half * 8;
#pragma unroll
    for (int w = 0; w < 8; ++w) {
      float2 fa = up2((int)p0[w]);
      float2 fb = up2((int)p1[w]);
      s1[w >> 1][(w & 1) * 2] = (fa.x + fb.x) * inv_v;
      s1[w >> 1][(w & 1) * 2 + 1] = (fa.y + fb.y) * inv_v;
    }
  }
  // ---- publish 16 f16 (2 quads), key1 = (v<<1)|(v&1); init packed accumulators ----
  const int myKey = (v << 1) | (v & 1);
  __half2 sp[8];
  {
    ivec4 w0, w1;
    w0[0] = pkrtz(s1[0][0], s1[0][1]); w0[1] = pkrtz(s1[0][2], s1[0][3]);
    w0[2] = pkrtz(s1[1][0], s1[1][1]); w0[3] = pkrtz(s1[1][2], s1[1][3]);
    w1[0] = pkrtz(s1[2][0], s1[2][1]); w1[1] = pkrtz(s1[2][2], s1[2][3]);
    w1[2] = pkrtz(s1[3][0], s1[3][1]); w1[3] = pkrtz(s1[3][2], s1[3][3]);
    buf[myKey] = w0;
    buf[myKey ^ 1] = w1;
    sp[0] = h2(w0[0]); sp[1] = h2(w0[1]); sp[2] = h2(w0[2]); sp[3] = h2(w0[3]);
    sp[4] = h2(w1[0]); sp[5] = h2(w1[1]); sp[6] = h2(w1[2]); sp[7] = h2(w1[3]);
  }
  __syncthreads();

  // ---- gather 16 feats (unroll x2, packed-f16 accumulation) ----
  {
    int e = nstart;
    const int end = nstart + count;
    for (; e + 2 <= end; e += 2) {
      const int la = sids[e], lb = sids[e + 1];
      const int Ka = (la << 1) | (la & 1), Kb = (lb << 1) | (lb & 1);
      const ivec4 a0_ = buf[Ka], a1_ = buf[Ka ^ 1];
      const ivec4 b0_ = buf[Kb], b1_ = buf[Kb ^ 1];
      ACCP(sp + 0, a0_) ACCP(sp + 4, a1_)
      ACCP(sp + 0, b0_) ACCP(sp + 4, b1_)
    }
    if (e < end) {
      const int la = sids[e];
      const int Ka = (la << 1) | (la & 1);
      const ivec4 a0_ = buf[Ka], a1_ = buf[Ka ^ 1];
      ACCP(sp + 0, a0_) ACCP(sp + 4, a1_)
    }
  }
  // ---- convert packed sums to f32 ----
#pragma unroll
  for (int w = 0; w < 8; ++w) {
    float2 f = __half22float2(sp[w]);
    s1[w >> 1][(w & 1) * 2] = f.x;
    s1[w >> 1][(w & 1) * 2 + 1] = f.y;
  }

  // ---- epilogue: h1_half = relu(s1*inv + b); hs1 slice; fold y2P = h1_half @ W2[half rows] ----
  const int slot = slot_of(v);
  const int hb = (side * BB + g) * 20;
  fvec4 y2P[4];
#pragma unroll
  for (int p = 0; p < 4; ++p) y2P[p] = fvec4{0.f, 0.f, 0.f, 0.f};
  {
    const fvec4* gb1v = reinterpret_cast<const fvec4*>(gb1 + half * 16);
    fvec4* hp = reinterpret_cast<fvec4*>(hs1 + ((size_t)hb + slot) * 32 + half * 16);
#pragma unroll
    for (int q = 0; q < 4; ++q) {
      fvec4 o = s1[q] * inv_v + gb1v[q];
#pragma unroll
      for (int j = 0; j < 4; ++j) o[j] = fmaxf(o[j], 0.f);
      if (slot >= 0) hp[q] = o;
#pragma unroll
      for (int j = 0; j < 4; ++j) {
        const float hf = o[j];
        const fvec4* wr = reinterpret_cast<const fvec4*>(gw2 + (size_t)(half * 16 + q * 4 + j) * 16);
#pragma unroll
        for (int p = 0; p < 4; ++p) y2P[p] += hf * wr[p];
      }
    }
  }
  {
    unsigned int* yp = y2G + ((size_t)(sg * 2 + half) * NPG + v) * 8;
#pragma unroll
    for (int w = 0; w < 8; ++w)
      yp[w] = (unsigned int)pkrtz(y2P[w >> 1][(w & 1) * 2], y2P[w >> 1][(w & 1) * 2 + 1]);
  }
}

// ================= kC: per (side,graph): L2 gather for sampled rows only =================
__global__ __launch_bounds__(512)
void kC(const float* __restrict__ gb2,
        const unsigned short* __restrict__ sidsG, const unsigned int* __restrict__ packG,
        const unsigned int* __restrict__ y2G, float* __restrict__ hs2) {
  __shared__ ivec4 buf[NPG * 2];          // 16 KB
  __shared__ unsigned short sids[EPG];    // 16 KB
  const int sg = blockIdx.x;
  const int side = sg >> 7, g = sg & 127;
  const int v = threadIdx.x;

  {
    const int* srcI = reinterpret_cast<const int*>(sidsG + (size_t)sg * EPG);
    int* dstI = reinterpret_cast<int*>(sids);
    for (int k = v; k < EPG / 2; k += 512) dstI[k] = srcI[k];
  }
  const unsigned int pack = packG[sg * NPG + v];
  const int count = (int)(pack & 0xffffu);
  const float inv_v = rsqrtf((float)count + 1.0f);

  // y2 full = sum of both halves' partials; publish msg = y2*inv (16 f16)
  const int myKey = (v << 1) | (v & 1);
  {
    const unsigned int* p0 = y2G + ((size_t)(sg * 2 + 0) * NPG + v) * 8;
    const unsigned int* p1 = y2G + ((size_t)(sg * 2 + 1) * NPG + v) * 8;
    fvec4 y2[4];
#pragma unroll
    for (int w = 0; w < 8; ++w) {
      float2 fa = up2((int)p0[w]);
      float2 fb = up2((int)p1[w]);
      y2[w >> 1][(w & 1) * 2] = (fa.x + fb.x) * inv_v;
      y2[w >> 1][(w & 1) * 2 + 1] = (fa.y + fb.y) * inv_v;
    }
    ivec4 w0, w1;
    w0[0] = pkrtz(y2[0][0], y2[0][1]); w0[1] = pkrtz(y2[0][2], y2[0][3]);
    w0[2] = pkrtz(y2[1][0], y2[1][1]); w0[3] = pkrtz(y2[1][2], y2[1][3]);
    w1[0] = pkrtz(y2[2][0], y2[2][1]); w1[1] = pkrtz(y2[2][2], y2[2][3]);
    w1[2] = pkrtz(y2[3][0], y2[3][1]); w1[3] = pkrtz(y2[3][2], y2[3][3]);
    buf[myKey] = w0;
    buf[myKey ^ 1] = w1;
  }
  __syncthreads();

  if (v < 20) {
    const int n = c_srows[v];
    const unsigned int cp = packG[sg * NPG + n];
    const int ccount = (int)(cp & 0xffffu);
    const int cstart = (int)(cp >> 16);
    const float cinv = rsqrtf((float)ccount + 1.0f);
    const int ckey = (n << 1) | (n & 1);
    __half2 sp[8];
    {
      const ivec4 w0 = buf[ckey], w1 = buf[ckey ^ 1];
      sp[0] = h2(w0[0]); sp[1] = h2(w0[1]); sp[2] = h2(w0[2]); sp[3] = h2(w0[3]);
      sp[4] = h2(w1[0]); sp[5] = h2(w1[1]); sp[6] = h2(w1[2]); sp[7] = h2(w1[3]);
    }
    for (int e = cstart; e < cstart + ccount; ++e) {
      const int la = sids[e];
      const int Ka = (la << 1) | (la & 1);
      const ivec4 w0 = buf[Ka], w1 = buf[Ka ^ 1];
      ACCP(sp + 0, w0) ACCP(sp + 4, w1)
    }
    const int hb = (side * BB + g) * 20;
    const fvec4* gb2v = reinterpret_cast<const fvec4*>(gb2);
    fvec4* hp = reinterpret_cast<fvec4*>(hs2 + ((size_t)hb + v) * 16);
#pragma unroll
    for (int q = 0; q < 4; ++q) {
      float2 f0 = __half22float2(sp[2 * q]);
      float2 f1 = __half22float2(sp[2 * q + 1]);
      fvec4 s2;
      s2[0] = f0.x; s2[1] = f0.y; s2[2] = f1.x; s2[3] = f1.y;
      hp[q] = s2 * cinv + gb2v[q];
    }
  }
}

// ---------------- head: sampled sim -> bilinear 10x10 -> conv3x3(1->8) -> MLP -> sigmoid ----------------
__global__ __launch_bounds__(256) void k_head(const float* __restrict__ hs0, const float* __restrict__ hs1,
                                              const float* __restrict__ hs2,
                                              const float* __restrict__ cw0, const float* __restrict__ cb0,
                                              const float* __restrict__ cw1, const float* __restrict__ cb1,
                                              const float* __restrict__ cw2, const float* __restrict__ cb2,
                                              const float* __restrict__ mw0, const float* __restrict__ mb0,
                                              const float* __restrict__ mw1, const float* __restrict__ mb1,
                                              const float* __restrict__ mw2, const float* __restrict__ mb2,
                                              const float* __restrict__ mw3, const float* __restrict__ mb3,
                                              const float* __restrict__ mw4, const float* __restrict__ mb4,
                                              const float* __restrict__ sw, const float* __restrict__ sb,
                                              float* __restrict__ out) {
  __shared__ float hi[2240];  // 20*64 + 20*32 + 20*16
  __shared__ float hj[2240];
  __shared__ float sim[400];
  __shared__ float simr[100];
  __shared__ float feat[2400];
  __shared__ float red[256];
  __shared__ float mbuf[60];
  const int b = blockIdx.x, t = threadIdx.x;

  for (int k = t; k < 1280; k += 256) {
    hi[k] = hs0[(size_t)(0 * BB + b) * 1280 + k];
    hj[k] = hs0[(size_t)(1 * BB + b) * 1280 + k];
  }
  for (int k = t; k < 640; k += 256) {
    hi[1280 + k] = hs1[(size_t)(0 * BB + b) * 640 + k];
    hj[1280 + k] = hs1[(size_t)(1 * BB + b) * 640 + k];
  }
  for (int k = t; k < 320; k += 256) {
    hi[1920 + k] = hs2[(size_t)(0 * BB + b) * 320 + k];
    hj[1920 + k] = hs2[(size_t)(1 * BB + b) * 320 + k];
  }
  __syncthreads();

  const int Fs[3] = {64, 32, 16};
  const int HOFF[3] = {0, 1280, 1920};
  const float* CW[3] = {cw0, cw1, cw2};
  const float* CB[3] = {cb0, cb1, cb2};

  for (int li = 0; li < 3; ++li) {
    const int F = Fs[li];
    const float* Hi = hi + HOFF[li];
    const float* Hj = hj + HOFF[li];
    for (int p = t; p < 400; p += 256) {
      int r = p / 20, cq = p % 20;
      float a = 0.0f;
      for (int d = 0; d < F; ++d) a += Hi[r * F + d] * Hj[cq * F + d];
      sim[p] = a;
    }
    __syncthreads();
    if (t < 100) {
      int oy = t / 10, ox = t % 10;
      float cy = (oy + 0.5f) * (512.0f / 10.0f) - 0.5f;
      float cx = (ox + 0.5f) * (512.0f / 10.0f) - 0.5f;
      float fy = cy - floorf(cy);
      float fx = cx - floorf(cx);
      int r0 = 2 * oy, c0 = 2 * ox;
      float s00 = sim[r0 * 20 + c0], s01 = sim[r0 * 20 + c0 + 1];
      float s10 = sim[(r0 + 1) * 20 + c0], s11 = sim[(r0 + 1) * 20 + c0 + 1];
      simr[t] = (1.0f - fy) * ((1.0f - fx) * s00 + fx * s01) + fy * ((1.0f - fx) * s10 + fx * s11);
    }
    __syncthreads();
    const float* cw = CW[li];
    const float* cb = CB[li];
    for (int idx = t; idx < 800; idx += 256) {
      int cch = idx / 100, rem = idx % 100, y = rem / 10, x = rem % 10;
      float a = cb[cch];
#pragma unroll
      for (int ky = 0; ky < 3; ++ky) {
#pragma unroll
        for (int kx = 0; kx < 3; ++kx) {
          int iy = y + ky - 1, ix = x + kx - 1;
          if (iy >= 0 && iy < 10 && ix >= 0 && ix < 10)
            a += cw[cch * 9 + ky * 3 + kx] * simr[iy * 10 + ix];
        }
      }
      feat[li * 800 + idx] = fmaxf(a, 0.0f);
    }
    __syncthreads();
  }

  // MLP0: 2400 -> 32, 8 partial sums per output
  {
    int f = t & 31, part = t >> 5;
    float a = 0.0f;
    int k0 = part * 300;
    for (int k = k0; k < k0 + 300; ++k) a += feat[k] * mw0[k * 32 + f];
    red[t] = a;
    __syncthreads();
    if (t < 32) {
      float s = mb0[t];
#pragma unroll
      for (int p = 0; p < 8; ++p) s += red[p * 32 + t];
      mbuf[t] = fmaxf(s, 0.0f);
    }
    __syncthreads();
  }
  if (t < 16) {
    float s = mb1[t];
    for (int k = 0; k < 32; ++k) s += mbuf[k] * mw1[k * 16 + t];
    mbuf[32 + t] = fmaxf(s, 0.0f);
  }
  __syncthreads();
  if (t < 8) {
    float s = mb2[t];
    for (int k = 0; k < 16; ++k) s += mbuf[32 + k] * mw2[k * 8 + t];
    mbuf[48 + t] = fmaxf(s, 0.0f);
  }
  __syncthreads();
  if (t < 4) {
    float s = mb3[t];
    for (int k = 0; k < 8; ++k) s += mbuf[48 + k] * mw3[k * 4 + t];
    mbuf[56 + t] = fmaxf(s, 0.0f);
  }
  __syncthreads();
  if (t == 0) {
    float s = mb4[0];
    for (int k = 0; k < 4; ++k) s += mbuf[56 + k] * mw4[k];
    s = fmaxf(s, 0.0f);
    float z = s * sw[0] + sb[0];
    out[b] = 1.0f / (1.0f + expf(-z));
  }
}

extern "C" void kernel_launch(void* const* d_in, const int* in_sizes, int n_in,
                              void* d_out, int out_size, void* d_ws, size_t ws_size,
                              hipStream_t stream) {
  (void)in_sizes; (void)n_in; (void)out_size; (void)ws_size;
  const float* x_i = (const float*)d_in[0];
  const float* x_j = (const float*)d_in[1];
  const float* gw0 = (const float*)d_in[2];
  const float* gb0 = (const float*)d_in[3];
  const float* gw1 = (const float*)d_in[4];
  const float* gb1 = (const float*)d_in[5];
  const float* gw2 = (const float*)d_in[6];
  const float* gb2 = (const float*)d_in[7];
  const float* cw0 = (const float*)d_in[8];
  const float* cb0 = (const float*)d_in[9];
  const float* cw1 = (const float*)d_in[10];
  const float* cb1 = (const float*)d_in[11];
  const float* cw2 = (const float*)d_in[12];
  const float* cb2 = (const float*)d_in[13];
  const float* mw0 = (const float*)d_in[14];
  const float* mb0 = (const float*)d_in[15];
  const float* mw1 = (const float*)d_in[16];
  const float* mb1 = (const float*)d_in[17];
  const float* mw2 = (const float*)d_in[18];
  const float* mb2 = (const float*)d_in[19];
  const float* mw3 = (const float*)d_in[20];
  const float* mb3 = (const float*)d_in[21];
  const float* mw4 = (const float*)d_in[22];
  const float* mb4 = (const float*)d_in[23];
  const float* scw = (const float*)d_in[24];
  const float* scb = (const float*)d_in[25];
  const int* ei = (const int*)d_in[26];
  const int* ej = (const int*)d_in[27];
  float* out = (float*)d_out;

  char* p = (char*)d_ws;
  auto take = [&](size_t bytes) {
    char* r = p;
    p += (bytes + 255) & ~(size_t)255;
    return r;
  };
  float* hs0 = (float*)take((size_t)2 * BB * 20 * 64 * 4);
  float* hs1 = (float*)take((size_t)2 * BB * 20 * 32 * 4);
  float* hs2 = (float*)take((size_t)2 * BB * 20 * 16 * 4);
  unsigned short* sidsG = (unsigned short*)take((size_t)2 * BB * EPG * 2);
  unsigned int* packG = (unsigned int*)take((size_t)2 * BB * NPG * 4);
  unsigned int* y1G = (unsigned int*)take((size_t)2 * BB * 2 * NPG * 16 * 4);
  unsigned int* y2G = (unsigned int*)take((size_t)2 * BB * 2 * NPG * 8 * 4);

  kA<<<2 * BB * 2, 512, 0, stream>>>(x_i, x_j, gw0, gb0, gw1, ei, ej,
                                     sidsG, packG, hs0, y1G);
  kB<<<2 * BB * 2, 512, 0, stream>>>(gb1, gw2, sidsG, packG, y1G, hs1, y2G);
  kC<<<2 * BB, 512, 0, stream>>>(gb2, sidsG, packG, y2G, hs2);
  k_head<<<BB, 256, 0, stream>>>(hs0, hs1, hs2, cw0, cb0, cw1, cb1, cw2, cb2,
                                 mw0, mb0, mw1, mb1, mw2, mb2, mw3, mb3, mw4, mb4,
                                 scw, scb, out);
}

// Round 25
// 116.680 us; speedup vs baseline: 1.0644x; 1.0220x over previous
//
#include <hip/hip_runtime.h>
#include <hip/hip_fp16.h>

typedef float fvec4 __attribute__((ext_vector_type(4)));
typedef int ivec4 __attribute__((ext_vector_type(4)));

#define NN 65536      // total nodes per side (B*NPG)
#define EE 1048576    // edges per side (B*NPG*DEG)
#define BB 128
#define NPG 512
#define EPG 8192      // edges per graph (NPG*DEG)

__device__ __forceinline__ int pkrtz(float a, float b) {
  union { __half2 h; int i; } u; u.h = __floats2half2_rn(a, b); return u.i;
}
__device__ __forceinline__ float2 up2(int v) {
  union { int i; __half2 h; } u; u.i = v; return __half22float2(u.h);
}
__device__ __forceinline__ __half2 h2(int v) {
  union { int i; __half2 h; } u; u.i = v; return u.h;
}

// packed-f16 accumulate: one 16B quad (8 f16) into 4 half2 accumulators (4 v_pk_add_f16)
#define ACCP(SP, w) { \
  (SP)[0] = __hadd2((SP)[0], h2((w)[0])); \
  (SP)[1] = __hadd2((SP)[1], h2((w)[1])); \
  (SP)[2] = __hadd2((SP)[2], h2((w)[2])); \
  (SP)[3] = __hadd2((SP)[3], h2((w)[3])); }

__device__ __forceinline__ int slot_of(int node) {
  constexpr int srows[20] = {25, 26, 76, 77, 127, 128, 178, 179, 229, 230,
                             281, 282, 332, 333, 383, 384, 434, 435, 485, 486};
  int slot = -1;
#pragma unroll
  for (int i = 0; i < 20; ++i)
    if (node == srows[i]) slot = i;
  return slot;
}
__constant__ int c_srows[20] = {25, 26, 76, 77, 127, 128, 178, 179, 229, 230,
                                281, 282, 332, 333, 383, 384, 434, 435, 485, 486};

// ================= kA: per (side,graph,half): CSR + degree-sort + L0 half + y1 partial ==========
// LDS ~48.5KB -> 3 blocks/CU. Prep arrays (dsts/cnt/posb/nodeOf/bins/binpos) alias buf and die
// before publish. Each thread owns node = nodeOf[v] (wave-uniform degrees). Outputs indexed
// by NODE (bijective per block) so kB's node-indexed reads are half-consistent.
__global__ __launch_bounds__(512)
void kA(const float* __restrict__ x_i, const float* __restrict__ x_j,
        const float* __restrict__ gw0, const float* __restrict__ gb0,
        const float* __restrict__ gw1,
        const int* __restrict__ ei, const int* __restrict__ ej,
        unsigned short* __restrict__ sidsG, unsigned int* __restrict__ packG,
        unsigned short* __restrict__ nodeOfG,
        float* __restrict__ hs0, unsigned int* __restrict__ y1G) {
  __shared__ ivec4 buf[NPG * 4];          // 32 KB f16 msg rows; prep aliases below
  __shared__ unsigned short sids[EPG];    // 16 KB
  __shared__ int wsum[8];
  char* const bufc = reinterpret_cast<char*>(buf);
  unsigned short* const dsts = reinterpret_cast<unsigned short*>(bufc);          // 16 KB @0
  int* const cnt = reinterpret_cast<int*>(bufc + 16384);                          // 2 KB
  int* const posb = reinterpret_cast<int*>(bufc + 18432);                         // 2 KB
  int* const nodeOf = reinterpret_cast<int*>(bufc + 20480);                       // 2 KB
  int* const bins = reinterpret_cast<int*>(bufc + 22528);                         // 256 B
  int* const binpos = reinterpret_cast<int*>(bufc + 22784);                       // 256 B

  const int bid = blockIdx.x;
  const int half = bid & 1;
  const int sg = bid >> 1;
  const int side = sg >> 7, g = sg & 127;
  const float* __restrict__ x = side ? x_j : x_i;
  const int* __restrict__ eidx = side ? ej : ei;
  const int v = threadIdx.x;
  const int base = g * NPG, ebase = g * EPG;

  // ---- degree count ----
  cnt[v] = 0;
  if (v < 64) bins[v] = 0;
  __syncthreads();
  for (int k = v; k < EPG; k += 512) {
    int d = eidx[EE + ebase + k] - base;
    dsts[k] = (unsigned short)d;
    atomicAdd(&cnt[d], 1);
  }
  __syncthreads();

  // ---- exclusive scan over 512 counts + degree histogram ----
  const int count = cnt[v];
  const int deg = count > 63 ? 63 : count;
  atomicAdd(&bins[deg], 1);
  int xa = count;
  const int lane = v & 63;
#pragma unroll
  for (int d = 1; d < 64; d <<= 1) {
    int y = __shfl_up(xa, d, 64);
    if (lane >= d) xa += y;
  }
  const int wid = v >> 6;
  if (lane == 63) wsum[wid] = xa;
  __syncthreads();
  if (v < 64) {
    if (v == 0) {
      int a = 0;
#pragma unroll
      for (int i = 0; i < 8; ++i) { int tv = wsum[i]; wsum[i] = a; a += tv; }
    }
    int c = bins[v];
    int xb = c;
#pragma unroll
    for (int d = 1; d < 64; d <<= 1) {
      int y = __shfl_up(xb, d, 64);
      if (v >= d) xb += y;
    }
    binpos[v] = xb - c;
  }
  __syncthreads();
  const int start = xa - count + wsum[wid];
  posb[v] = start;
  if (half == 0) packG[sg * NPG + v] = ((unsigned int)start << 16) | (unsigned int)count;
  {
    int rank = atomicAdd(&binpos[deg], 1);
    nodeOf[rank] = v;
  }
  __syncthreads();

  // ---- CSR fill (bucket by dst), raw ids ----
  for (int k = v; k < EPG; k += 512) {
    int lv = eidx[ebase + k] - base;
    int p = atomicAdd(&posb[dsts[k]], 1);
    sids[p] = (unsigned short)lv;
  }
  __syncthreads();  // fill complete; nodeOf/cnt/posb readable

  // ---- per-thread node assignment (wave-uniform degrees); read before buf clobber ----
  const int node = nodeOf[v];
  const int ncount = cnt[node];
  const int nstart = posb[node] - ncount;  // posb bumped to end by fill
  if (half == 0) nodeOfG[sg * NPG + v] = (unsigned short)node;

  // ---- L0 half-GEMM: a0 = x_row(node) @ W0[:, half*32 : half*32+32] ----
  fvec4 a0[8];
#pragma unroll
  for (int q = 0; q < 8; ++q) a0[q] = fvec4{0.f, 0.f, 0.f, 0.f};
  {
    const fvec4* xv = reinterpret_cast<const fvec4*>(x + (size_t)(base + node) * 64);
    const float* w0h = gw0 + half * 32;
#pragma unroll 1
    for (int k16 = 0; k16 < 4; ++k16) {
      fvec4 xq[4];
#pragma unroll
      for (int u = 0; u < 4; ++u) xq[u] = xv[4 * k16 + u];
#pragma unroll
      for (int u = 0; u < 4; ++u) {
#pragma unroll
        for (int j = 0; j < 4; ++j) {
          const float xk = xq[u][j];
          const fvec4* wr = reinterpret_cast<const fvec4*>(w0h + (size_t)(16 * k16 + 4 * u + j) * 64);
#pragma unroll
          for (int q = 0; q < 8; ++q) a0[q] += xk * wr[q];
        }
      }
    }
  }
  __syncthreads();  // all prep reads done -> buf reusable

  // ---- export CSR once (half 0) for kB/kC ----
  if (half == 0) {
    const int* srcI = reinterpret_cast<const int*>(sids);
    int* dstI = reinterpret_cast<int*>(sidsG + (size_t)sg * EPG);
    for (int k = v; k < EPG / 2; k += 512) dstI[k] = srcI[k];
  }

  // ---- publish own messages (f16, swizzled); init packed accumulators with same bits ----
  const float inv_v = rsqrtf((float)ncount + 1.0f);
  const int myKey = (node << 2) | ((node >> 1) & 3);
  __half2 sp[16];
#pragma unroll
  for (int q_ = 0; q_ < 4; ++q_) {
    fvec4 m0 = a0[2 * q_] * inv_v;
    fvec4 m1 = a0[2 * q_ + 1] * inv_v;
    ivec4 w_;
    w_[0] = pkrtz(m0[0], m0[1]);
    w_[1] = pkrtz(m0[2], m0[3]);
    w_[2] = pkrtz(m1[0], m1[1]);
    w_[3] = pkrtz(m1[2], m1[3]);
    buf[myKey ^ q_] = w_;
    sp[4 * q_ + 0] = h2(w_[0]);
    sp[4 * q_ + 1] = h2(w_[1]);
    sp[4 * q_ + 2] = h2(w_[2]);
    sp[4 * q_ + 3] = h2(w_[3]);
  }
  __syncthreads();

  // ---- gather 32 feats (unroll x2, packed-f16 accumulation) ----
  {
    int e = nstart;
    const int end = nstart + ncount;
    for (; e + 2 <= end; e += 2) {
      const int la = sids[e], lb = sids[e + 1];
      const int Ka = (la << 2) | ((la >> 1) & 3);
      const int Kb = (lb << 2) | ((lb >> 1) & 3);
      const ivec4 a0_ = buf[Ka], a1_ = buf[Ka ^ 1], a2_ = buf[Ka ^ 2], a3_ = buf[Ka ^ 3];
      const ivec4 b0_ = buf[Kb], b1_ = buf[Kb ^ 1], b2_ = buf[Kb ^ 2], b3_ = buf[Kb ^ 3];
      ACCP(sp + 0, a0_) ACCP(sp + 4, a1_) ACCP(sp + 8, a2_) ACCP(sp + 12, a3_)
      ACCP(sp + 0, b0_) ACCP(sp + 4, b1_) ACCP(sp + 8, b2_) ACCP(sp + 12, b3_)
    }
    if (e < end) {
      const int la = sids[e];
      const int Ka = (la << 2) | ((la >> 1) & 3);
      const ivec4 a0_ = buf[Ka], a1_ = buf[Ka ^ 1], a2_ = buf[Ka ^ 2], a3_ = buf[Ka ^ 3];
      ACCP(sp + 0, a0_) ACCP(sp + 4, a1_) ACCP(sp + 8, a2_) ACCP(sp + 12, a3_)
    }
  }

  // ---- convert packed sums to f32 ----
  fvec4 s[8];
#pragma unroll
  for (int q_ = 0; q_ < 4; ++q_) {
    float2 f0 = __half22float2(sp[4 * q_ + 0]);
    float2 f1 = __half22float2(sp[4 * q_ + 1]);
    float2 f2 = __half22float2(sp[4 * q_ + 2]);
    float2 f3 = __half22float2(sp[4 * q_ + 3]);
    s[2 * q_][0] = f0.x; s[2 * q_][1] = f0.y; s[2 * q_][2] = f1.x; s[2 * q_][3] = f1.y;
    s[2 * q_ + 1][0] = f2.x; s[2 * q_ + 1][1] = f2.y; s[2 * q_ + 1][2] = f3.x; s[2 * q_ + 1][3] = f3.y;
  }

  // ---- epilogue: h0_half = relu(s*inv + b); hs0 slice; fold y1P = h0_half @ W1[half rows] ----
  const int slot = slot_of(node);
  const int hb = (side * BB + g) * 20;
  fvec4 y1P[8];
#pragma unroll
  for (int p = 0; p < 8; ++p) y1P[p] = fvec4{0.f, 0.f, 0.f, 0.f};
  {
    const fvec4* gb0v = reinterpret_cast<const fvec4*>(gb0 + half * 32);
    fvec4* hp = reinterpret_cast<fvec4*>(hs0 + ((size_t)hb + slot) * 64 + half * 32);
#pragma unroll
    for (int q = 0; q < 8; ++q) {
      fvec4 o = s[q] * inv_v + gb0v[q];
#pragma unroll
      for (int j = 0; j < 4; ++j) o[j] = fmaxf(o[j], 0.f);
      if (slot >= 0) hp[q] = o;
#pragma unroll
      for (int j = 0; j < 4; ++j) {
        const float hf = o[j];
        const fvec4* wr = reinterpret_cast<const fvec4*>(gw1 + (size_t)(half * 32 + q * 4 + j) * 32);
#pragma unroll
        for (int p = 0; p < 8; ++p) y1P[p] += hf * wr[p];
      }
    }
  }
  // ---- write y1 partial at NODE index (bijective per block; half-consistent for kB) ----
  {
    unsigned int* yp = y1G + ((size_t)(sg * 2 + half) * NPG + node) * 16;
#pragma unroll
    for (int w = 0; w < 16; ++w)
      yp[w] = (unsigned int)pkrtz(y1P[w >> 1][(w & 1) * 2], y1P[w >> 1][(w & 1) * 2 + 1]);
  }
}

// ================= kB: per (side,graph,half): L1 (16-feat slice) + y2 partial =================
// Thread v owns node = nodeOfG[v] (degree-sorted, wave-uniform trip counts).
__global__ __launch_bounds__(512)
void kB(const float* __restrict__ gb1, const float* __restrict__ gw2,
        const unsigned short* __restrict__ sidsG, const unsigned int* __restrict__ packG,
        const unsigned short* __restrict__ nodeOfG, const unsigned int* __restrict__ y1G,
        float* __restrict__ hs1, unsigned int* __restrict__ y2G) {
  __shared__ ivec4 buf[NPG * 2];          // 16 KB: msg rows of 2 quads
  __shared__ unsigned short sids[EPG];    // 16 KB
  const int bid = blockIdx.x;
  const int half = bid & 1;
  const int sg = bid >> 1;
  const int side = sg >> 7, g = sg & 127;
  const int v = threadIdx.x;

  {
    const int* srcI = reinterpret_cast<const int*>(sidsG + (size_t)sg * EPG);
    int* dstI = reinterpret_cast<int*>(sids);
    for (int k = v; k < EPG / 2; k += 512) dstI[k] = srcI[k];
  }
  const int node = nodeOfG[sg * NPG + v];
  const unsigned int pack = packG[sg * NPG + node];
  const int count = (int)(pack & 0xffffu);
  const int nstart = (int)(pack >> 16);
  const float inv_v = rsqrtf((float)count + 1.0f);

  // ---- y1 slice = sum of both halves' partials (16 f32), node-indexed ----
  fvec4 s1[4];
  {
    const unsigned int* p0 = y1G + ((size_t)(sg * 2 + 0) * NPG + node) * 16 + half * 8;
    const unsigned int* p1 = y1G + ((size_t)(sg * 2 + 1) * NPG + node) * 16 + half * 8;
#pragma unroll
    for (int w = 0; w < 8; ++w) {
      float2 fa = up2((int)p0[w]);
      float2 fb = up2((int)p1[w]);
      s1[w >> 1][(w & 1) * 2] = (fa.x + fb.x) * inv_v;
      s1[w >> 1][(w & 1) * 2 + 1] = (fa.y + fb.y) * inv_v;
    }
  }
  // ---- publish 16 f16 (2 quads), key1 from node; init packed accumulators ----
  const int myKey = (node << 1) | (node & 1);
  __half2 sp[8];
  {
    ivec4 w0, w1;
    w0[0] = pkrtz(s1[0][0], s1[0][1]); w0[1] = pkrtz(s1[0][2], s1[0][3]);
    w0[2] = pkrtz(s1[1][0], s1[1][1]); w0[3] = pkrtz(s1[1][2], s1[1][3]);
    w1[0] = pkrtz(s1[2][0], s1[2][1]); w1[1] = pkrtz(s1[2][2], s1[2][3]);
    w1[2] = pkrtz(s1[3][0], s1[3][1]); w1[3] = pkrtz(s1[3][2], s1[3][3]);
    buf[myKey] = w0;
    buf[myKey ^ 1] = w1;
    sp[0] = h2(w0[0]); sp[1] = h2(w0[1]); sp[2] = h2(w0[2]); sp[3] = h2(w0[3]);
    sp[4] = h2(w1[0]); sp[5] = h2(w1[1]); sp[6] = h2(w1[2]); sp[7] = h2(w1[3]);
  }
  __syncthreads();

  // ---- gather 16 feats (unroll x2, packed-f16 accumulation) ----
  {
    int e = nstart;
    const int end = nstart + count;
    for (; e + 2 <= end; e += 2) {
      const int la = sids[e], lb = sids[e + 1];
      const int Ka = (la << 1) | (la & 1), Kb = (lb << 1) | (lb & 1);
      const ivec4 a0_ = buf[Ka], a1_ = buf[Ka ^ 1];
      const ivec4 b0_ = buf[Kb], b1_ = buf[Kb ^ 1];
      ACCP(sp + 0, a0_) ACCP(sp + 4, a1_)
      ACCP(sp + 0, b0_) ACCP(sp + 4, b1_)
    }
    if (e < end) {
      const int la = sids[e];
      const int Ka = (la << 1) | (la & 1);
      const ivec4 a0_ = buf[Ka], a1_ = buf[Ka ^ 1];
      ACCP(sp + 0, a0_) ACCP(sp + 4, a1_)
    }
  }
  // ---- convert packed sums to f32 ----
#pragma unroll
  for (int w = 0; w < 8; ++w) {
    float2 f = __half22float2(sp[w]);
    s1[w >> 1][(w & 1) * 2] = f.x;
    s1[w >> 1][(w & 1) * 2 + 1] = f.y;
  }

  // ---- epilogue: h1_half = relu(s1*inv + b); hs1 slice; fold y2P = h1_half @ W2[half rows] ----
  const int slot = slot_of(node);
  const int hb = (side * BB + g) * 20;
  fvec4 y2P[4];
#pragma unroll
  for (int p = 0; p < 4; ++p) y2P[p] = fvec4{0.f, 0.f, 0.f, 0.f};
  {
    const fvec4* gb1v = reinterpret_cast<const fvec4*>(gb1 + half * 16);
    fvec4* hp = reinterpret_cast<fvec4*>(hs1 + ((size_t)hb + slot) * 32 + half * 16);
#pragma unroll
    for (int q = 0; q < 4; ++q) {
      fvec4 o = s1[q] * inv_v + gb1v[q];
#pragma unroll
      for (int j = 0; j < 4; ++j) o[j] = fmaxf(o[j], 0.f);
      if (slot >= 0) hp[q] = o;
#pragma unroll
      for (int j = 0; j < 4; ++j) {
        const float hf = o[j];
        const fvec4* wr = reinterpret_cast<const fvec4*>(gw2 + (size_t)(half * 16 + q * 4 + j) * 16);
#pragma unroll
        for (int p = 0; p < 4; ++p) y2P[p] += hf * wr[p];
      }
    }
  }
  {
    unsigned int* yp = y2G + ((size_t)(sg * 2 + half) * NPG + node) * 8;
#pragma unroll
    for (int w = 0; w < 8; ++w)
      yp[w] = (unsigned int)pkrtz(y2P[w >> 1][(w & 1) * 2], y2P[w >> 1][(w & 1) * 2 + 1]);
  }
}

// ================= kC: per (side,graph): L2 gather for sampled rows only =================
__global__ __launch_bounds__(512)
void kC(const float* __restrict__ gb2,
        const unsigned short* __restrict__ sidsG, const unsigned int* __restrict__ packG,
        const unsigned int* __restrict__ y2G, float* __restrict__ hs2) {
  __shared__ ivec4 buf[NPG * 2];          // 16 KB
  __shared__ unsigned short sids[EPG];    // 16 KB
  const int sg = blockIdx.x;
  const int side = sg >> 7, g = sg & 127;
  const int v = threadIdx.x;

  {
    const int* srcI = reinterpret_cast<const int*>(sidsG + (size_t)sg * EPG);
    int* dstI = reinterpret_cast<int*>(sids);
    for (int k = v; k < EPG / 2; k += 512) dstI[k] = srcI[k];
  }
  const unsigned int pack = packG[sg * NPG + v];
  const int count = (int)(pack & 0xffffu);
  const float inv_v = rsqrtf((float)count + 1.0f);

  // y2 full = sum of both halves' partials (node v); publish msg = y2*inv (16 f16)
  const int myKey = (v << 1) | (v & 1);
  {
    const unsigned int* p0 = y2G + ((size_t)(sg * 2 + 0) * NPG + v) * 8;
    const unsigned int* p1 = y2G + ((size_t)(sg * 2 + 1) * NPG + v) * 8;
    fvec4 y2[4];
#pragma unroll
    for (int w = 0; w < 8; ++w) {
      float2 fa = up2((int)p0[w]);
      float2 fb = up2((int)p1[w]);
      y2[w >> 1][(w & 1) * 2] = (fa.x + fb.x) * inv_v;
      y2[w >> 1][(w & 1) * 2 + 1] = (fa.y + fb.y) * inv_v;
    }
    ivec4 w0, w1;
    w0[0] = pkrtz(y2[0][0], y2[0][1]); w0[1] = pkrtz(y2[0][2], y2[0][3]);
    w0[2] = pkrtz(y2[1][0], y2[1][1]); w0[3] = pkrtz(y2[1][2], y2[1][3]);
    w1[0] = pkrtz(y2[2][0], y2[2][1]); w1[1] = pkrtz(y2[2][2], y2[2][3]);
    w1[2] = pkrtz(y2[3][0], y2[3][1]); w1[3] = pkrtz(y2[3][2], y2[3][3]);
    buf[myKey] = w0;
    buf[myKey ^ 1] = w1;
  }
  __syncthreads();

  if (v < 20) {
    const int n = c_srows[v];
    const unsigned int cp = packG[sg * NPG + n];
    const int ccount = (int)(cp & 0xffffu);
    const int cstart = (int)(cp >> 16);
    const float cinv = rsqrtf((float)ccount + 1.0f);
    const int ckey = (n << 1) | (n & 1);
    __half2 sp[8];
    {
      const ivec4 w0 = buf[ckey], w1 = buf[ckey ^ 1];
      sp[0] = h2(w0[0]); sp[1] = h2(w0[1]); sp[2] = h2(w0[2]); sp[3] = h2(w0[3]);
      sp[4] = h2(w1[0]); sp[5] = h2(w1[1]); sp[6] = h2(w1[2]); sp[7] = h2(w1[3]);
    }
    for (int e = cstart; e < cstart + ccount; ++e) {
      const int la = sids[e];
      const int Ka = (la << 1) | (la & 1);
      const ivec4 w0 = buf[Ka], w1 = buf[Ka ^ 1];
      ACCP(sp + 0, w0) ACCP(sp + 4, w1)
    }
    const int hb = (side * BB + g) * 20;
    const fvec4* gb2v = reinterpret_cast<const fvec4*>(gb2);
    fvec4* hp = reinterpret_cast<fvec4*>(hs2 + ((size_t)hb + v) * 16);
#pragma unroll
    for (int q = 0; q < 4; ++q) {
      float2 f0 = __half22float2(sp[2 * q]);
      float2 f1 = __half22float2(sp[2 * q + 1]);
      fvec4 s2;
      s2[0] = f0.x; s2[1] = f0.y; s2[2] = f1.x; s2[3] = f1.y;
      hp[q] = s2 * cinv + gb2v[q];
    }
  }
}

// ---------------- head: sampled sim -> bilinear 10x10 -> conv3x3(1->8) -> MLP -> sigmoid ----------------
__global__ __launch_bounds__(256) void k_head(const float* __restrict__ hs0, const float* __restrict__ hs1,
                                              const float* __restrict__ hs2,
                                              const float* __restrict__ cw0, const float* __restrict__ cb0,
                                              const float* __restrict__ cw1, const float* __restrict__ cb1,
                                              const float* __restrict__ cw2, const float* __restrict__ cb2,
                                              const float* __restrict__ mw0, const float* __restrict__ mb0,
                                              const float* __restrict__ mw1, const float* __restrict__ mb1,
                                              const float* __restrict__ mw2, const float* __restrict__ mb2,
                                              const float* __restrict__ mw3, const float* __restrict__ mb3,
                                              const float* __restrict__ mw4, const float* __restrict__ mb4,
                                              const float* __restrict__ sw, const float* __restrict__ sb,
                                              float* __restrict__ out) {
  __shared__ float hi[2240];  // 20*64 + 20*32 + 20*16
  __shared__ float hj[2240];
  __shared__ float sim[400];
  __shared__ float simr[100];
  __shared__ float feat[2400];
  __shared__ float red[256];
  __shared__ float mbuf[60];
  const int b = blockIdx.x, t = threadIdx.x;

  for (int k = t; k < 1280; k += 256) {
    hi[k] = hs0[(size_t)(0 * BB + b) * 1280 + k];
    hj[k] = hs0[(size_t)(1 * BB + b) * 1280 + k];
  }
  for (int k = t; k < 640; k += 256) {
    hi[1280 + k] = hs1[(size_t)(0 * BB + b) * 640 + k];
    hj[1280 + k] = hs1[(size_t)(1 * BB + b) * 640 + k];
  }
  for (int k = t; k < 320; k += 256) {
    hi[1920 + k] = hs2[(size_t)(0 * BB + b) * 320 + k];
    hj[1920 + k] = hs2[(size_t)(1 * BB + b) * 320 + k];
  }
  __syncthreads();

  const int Fs[3] = {64, 32, 16};
  const int HOFF[3] = {0, 1280, 1920};
  const float* CW[3] = {cw0, cw1, cw2};
  const float* CB[3] = {cb0, cb1, cb2};

  for (int li = 0; li < 3; ++li) {
    const int F = Fs[li];
    const float* Hi = hi + HOFF[li];
    const float* Hj = hj + HOFF[li];
    for (int p = t; p < 400; p += 256) {
      int r = p / 20, cq = p % 20;
      float a = 0.0f;
      for (int d = 0; d < F; ++d) a += Hi[r * F + d] * Hj[cq * F + d];
      sim[p] = a;
    }
    __syncthreads();
    if (t < 100) {
      int oy = t / 10, ox = t % 10;
      float cy = (oy + 0.5f) * (512.0f / 10.0f) - 0.5f;
      float cx = (ox + 0.5f) * (512.0f / 10.0f) - 0.5f;
      float fy = cy - floorf(cy);
      float fx = cx - floorf(cx);
      int r0 = 2 * oy, c0 = 2 * ox;
      float s00 = sim[r0 * 20 + c0], s01 = sim[r0 * 20 + c0 + 1];
      float s10 = sim[(r0 + 1) * 20 + c0], s11 = sim[(r0 + 1) * 20 + c0 + 1];
      simr[t] = (1.0f - fy) * ((1.0f - fx) * s00 + fx * s01) + fy * ((1.0f - fx) * s10 + fx * s11);
    }
    __syncthreads();
    const float* cw = CW[li];
    const float* cb = CB[li];
    for (int idx = t; idx < 800; idx += 256) {
      int cch = idx / 100, rem = idx % 100, y = rem / 10, x = rem % 10;
      float a = cb[cch];
#pragma unroll
      for (int ky = 0; ky < 3; ++ky) {
#pragma unroll
        for (int kx = 0; kx < 3; ++kx) {
          int iy = y + ky - 1, ix = x + kx - 1;
          if (iy >= 0 && iy < 10 && ix >= 0 && ix < 10)
            a += cw[cch * 9 + ky * 3 + kx] * simr[iy * 10 + ix];
        }
      }
      feat[li * 800 + idx] = fmaxf(a, 0.0f);
    }
    __syncthreads();
  }

  // MLP0: 2400 -> 32, 8 partial sums per output
  {
    int f = t & 31, part = t >> 5;
    float a = 0.0f;
    int k0 = part * 300;
    for (int k = k0; k < k0 + 300; ++k) a += feat[k] * mw0[k * 32 + f];
    red[t] = a;
    __syncthreads();
    if (t < 32) {
      float s = mb0[t];
#pragma unroll
      for (int p = 0; p < 8; ++p) s += red[p * 32 + t];
      mbuf[t] = fmaxf(s, 0.0f);
    }
    __syncthreads();
  }
  if (t < 16) {
    float s = mb1[t];
    for (int k = 0; k < 32; ++k) s += mbuf[k] * mw1[k * 16 + t];
    mbuf[32 + t] = fmaxf(s, 0.0f);
  }
  __syncthreads();
  if (t < 8) {
    float s = mb2[t];
    for (int k = 0; k < 16; ++k) s += mbuf[32 + k] * mw2[k * 8 + t];
    mbuf[48 + t] = fmaxf(s, 0.0f);
  }
  __syncthreads();
  if (t < 4) {
    float s = mb3[t];
    for (int k = 0; k < 8; ++k) s += mbuf[48 + k] * mw3[k * 4 + t];
    mbuf[56 + t] = fmaxf(s, 0.0f);
  }
  __syncthreads();
  if (t == 0) {
    float s = mb4[0];
    for (int k = 0; k < 4; ++k) s += mbuf[56 + k] * mw4[k];
    s = fmaxf(s, 0.0f);
    float z = s * sw[0] + sb[0];
    out[b] = 1.0f / (1.0f + expf(-z));
  }
}

extern "C" void kernel_launch(void* const* d_in, const int* in_sizes, int n_in,
                              void* d_out, int out_size, void* d_ws, size_t ws_size,
                              hipStream_t stream) {
  (void)in_sizes; (void)n_in; (void)out_size; (void)ws_size;
  const float* x_i = (const float*)d_in[0];
  const float* x_j = (const float*)d_in[1];
  const float* gw0 = (const float*)d_in[2];
  const float* gb0 = (const float*)d_in[3];
  const float* gw1 = (const float*)d_in[4];
  const float* gb1 = (const float*)d_in[5];
  const float* gw2 = (const float*)d_in[6];
  const float* gb2 = (const float*)d_in[7];
  const float* cw0 = (const float*)d_in[8];
  const float* cb0 = (const float*)d_in[9];
  const float* cw1 = (const float*)d_in[10];
  const float* cb1 = (const float*)d_in[11];
  const float* cw2 = (const float*)d_in[12];
  const float* cb2 = (const float*)d_in[13];
  const float* mw0 = (const float*)d_in[14];
  const float* mb0 = (const float*)d_in[15];
  const float* mw1 = (const float*)d_in[16];
  const float* mb1 = (const float*)d_in[17];
  const float* mw2 = (const float*)d_in[18];
  const float* mb2 = (const float*)d_in[19];
  const float* mw3 = (const float*)d_in[20];
  const float* mb3 = (const float*)d_in[21];
  const float* mw4 = (const float*)d_in[22];
  const float* mb4 = (const float*)d_in[23];
  const float* scw = (const float*)d_in[24];
  const float* scb = (const float*)d_in[25];
  const int* ei = (const int*)d_in[26];
  const int* ej = (const int*)d_in[27];
  float* out = (float*)d_out;

  char* p = (char*)d_ws;
  auto take = [&](size_t bytes) {
    char* r = p;
    p += (bytes + 255) & ~(size_t)255;
    return r;
  };
  float* hs0 = (float*)take((size_t)2 * BB * 20 * 64 * 4);
  float* hs1 = (float*)take((size_t)2 * BB * 20 * 32 * 4);
  float* hs2 = (float*)take((size_t)2 * BB * 20 * 16 * 4);
  unsigned short* sidsG = (unsigned short*)take((size_t)2 * BB * EPG * 2);
  unsigned int* packG = (unsigned int*)take((size_t)2 * BB * NPG * 4);
  unsigned short* nodeOfG = (unsigned short*)take((size_t)2 * BB * NPG * 2);
  unsigned int* y1G = (unsigned int*)take((size_t)2 * BB * 2 * NPG * 16 * 4);
  unsigned int* y2G = (unsigned int*)take((size_t)2 * BB * 2 * NPG * 8 * 4);

  kA<<<2 * BB * 2, 512, 0, stream>>>(x_i, x_j, gw0, gb0, gw1, ei, ej,
                                     sidsG, packG, nodeOfG, hs0, y1G);
  kB<<<2 * BB * 2, 512, 0, stream>>>(gb1, gw2, sidsG, packG, nodeOfG, y1G, hs1, y2G);
  kC<<<2 * BB, 512, 0, stream>>>(gb2, sidsG, packG, y2G, hs2);
  k_head<<<BB, 256, 0, stream>>>(hs0, hs1, hs2, cw0, cb0, cw1, cb1, cw2, cb2,
                                 mw0, mb0, mw1, mb1, mw2, mb2, mw3, mb3, mw4, mb4,
                                 scw, scb, out);
}